// Round 1
// baseline (2081.302 us; speedup 1.0000x reference)
//
#include <hip/hip_runtime.h>

#define BN_EPS 1e-5f

// ---------------------------------------------------------------------------
// scatter-add for F=128 features: 32 threads per edge, float4 per thread
// ---------------------------------------------------------------------------
__global__ void scatter128(const float* __restrict__ x, const int* __restrict__ src,
                           const int* __restrict__ dst, float* __restrict__ agg, int E) {
    int t = blockIdx.x * blockDim.x + threadIdx.x;
    int e = t >> 5;
    if (e >= E) return;
    int c = (t & 31) * 4;
    int s = src[e];
    int d = dst[e];
    const float4 v = *reinterpret_cast<const float4*>(x + (size_t)s * 128 + c);
    float* a = agg + (size_t)d * 128 + c;
    atomicAdd(a + 0, v.x);
    atomicAdd(a + 1, v.y);
    atomicAdd(a + 2, v.z);
    atomicAdd(a + 3, v.w);
}

// ---------------------------------------------------------------------------
// scatter-add for D=32 features: 8 threads per edge, float4 per thread
// ---------------------------------------------------------------------------
__global__ void scatter32(const float* __restrict__ h, const int* __restrict__ src,
                          const int* __restrict__ dst, float* __restrict__ agg, int E) {
    int t = blockIdx.x * blockDim.x + threadIdx.x;
    int e = t >> 3;
    if (e >= E) return;
    int c = (t & 7) * 4;
    int s = src[e];
    int d = dst[e];
    const float4 v = *reinterpret_cast<const float4*>(h + (size_t)s * 32 + c);
    float* a = agg + (size_t)d * 32 + c;
    atomicAdd(a + 0, v.x);
    atomicAdd(a + 1, v.y);
    atomicAdd(a + 2, v.z);
    atomicAdd(a + 3, v.w);
}

// ---------------------------------------------------------------------------
// Layer 1: out = BN(relu( relu((x+agg) @ Wa + ba) @ Wb + bb ))
// block = 256 threads = 8 nodes x 32 features
// ---------------------------------------------------------------------------
__global__ void mlp_layer1(const float* __restrict__ x, const float* __restrict__ agg,
                           const float* __restrict__ Wa, const float* __restrict__ ba,
                           const float* __restrict__ Wb, const float* __restrict__ bb,
                           const float* __restrict__ g, const float* __restrict__ be,
                           const float* __restrict__ m, const float* __restrict__ v,
                           float* __restrict__ out, int n) {
    __shared__ float sWa[128 * 32];
    __shared__ float sWb[32 * 32];
    __shared__ float sIn[8][128];
    __shared__ float sT[8][32];

    int tid = threadIdx.x;
    for (int i = tid; i < 128 * 32; i += 256) sWa[i] = Wa[i];
    for (int i = tid; i < 32 * 32; i += 256) sWb[i] = Wb[i];

    int node0 = blockIdx.x * 8;
    int r = tid >> 5;
    int node = node0 + r;
    {
        int c = (tid & 31) * 4;
        if (node < n) {
            const float4 xv = *reinterpret_cast<const float4*>(x + (size_t)node * 128 + c);
            const float4 av = *reinterpret_cast<const float4*>(agg + (size_t)node * 128 + c);
            sIn[r][c + 0] = xv.x + av.x;
            sIn[r][c + 1] = xv.y + av.y;
            sIn[r][c + 2] = xv.z + av.z;
            sIn[r][c + 3] = xv.w + av.w;
        }
    }
    __syncthreads();

    int f = tid & 31;
    float acc = ba[f];
    #pragma unroll 8
    for (int k = 0; k < 128; k++) acc += sIn[r][k] * sWa[k * 32 + f];
    acc = fmaxf(acc, 0.0f);
    sT[r][f] = acc;
    __syncthreads();

    float acc2 = bb[f];
    #pragma unroll
    for (int k = 0; k < 32; k++) acc2 += sT[r][k] * sWb[k * 32 + f];
    acc2 = fmaxf(acc2, 0.0f);  // outer relu
    float bn = (acc2 - m[f]) * rsqrtf(v[f] + BN_EPS) * g[f] + be[f];
    if (node < n) out[(size_t)node * 32 + f] = bn;
}

// ---------------------------------------------------------------------------
// Layers 2/3: out = BN(relu( relu((h+agg) @ Wa + ba) @ Wb + bb ))
// block = 256 threads = 8 nodes x 32 features
// ---------------------------------------------------------------------------
__global__ void mlp_layer32(const float* __restrict__ hin, const float* __restrict__ agg,
                            const float* __restrict__ Wa, const float* __restrict__ ba,
                            const float* __restrict__ Wb, const float* __restrict__ bb,
                            const float* __restrict__ g, const float* __restrict__ be,
                            const float* __restrict__ m, const float* __restrict__ v,
                            float* __restrict__ out, int n) {
    __shared__ float sWa[32 * 32];
    __shared__ float sWb[32 * 32];
    __shared__ float sIn[8][32];
    __shared__ float sT[8][32];

    int tid = threadIdx.x;
    for (int i = tid; i < 32 * 32; i += 256) {
        sWa[i] = Wa[i];
        sWb[i] = Wb[i];
    }

    int node0 = blockIdx.x * 8;
    int r = tid >> 5;
    int f = tid & 31;
    int node = node0 + r;
    if (node < n) {
        sIn[r][f] = hin[(size_t)node * 32 + f] + agg[(size_t)node * 32 + f];
    }
    __syncthreads();

    float acc = ba[f];
    #pragma unroll
    for (int k = 0; k < 32; k++) acc += sIn[r][k] * sWa[k * 32 + f];
    acc = fmaxf(acc, 0.0f);
    sT[r][f] = acc;
    __syncthreads();

    float acc2 = bb[f];
    #pragma unroll
    for (int k = 0; k < 32; k++) acc2 += sT[r][k] * sWb[k * 32 + f];
    acc2 = fmaxf(acc2, 0.0f);
    float bn = (acc2 - m[f]) * rsqrtf(v[f] + BN_EPS) * g[f] + be[f];
    if (node < n) out[(size_t)node * 32 + f] = bn;
}

// ---------------------------------------------------------------------------
// Final head: out = log_softmax( relu(h @ Wf1 + bf1) @ Wf2 + bf2 )
// block = 256 threads = 8 nodes x 32 features
// ---------------------------------------------------------------------------
__global__ void final_head(const float* __restrict__ h,
                           const float* __restrict__ W1, const float* __restrict__ b1,
                           const float* __restrict__ W2, const float* __restrict__ b2,
                           float* __restrict__ out, int n) {
    __shared__ float sW1[32 * 32];
    __shared__ float sW2[32 * 10];
    __shared__ float sIn[8][32];
    __shared__ float sT[8][32];
    __shared__ float sZ[8][12];

    int tid = threadIdx.x;
    for (int i = tid; i < 32 * 32; i += 256) sW1[i] = W1[i];
    for (int i = tid; i < 32 * 10; i += 256) sW2[i] = W2[i];

    int node0 = blockIdx.x * 8;
    int r = tid >> 5;
    int f = tid & 31;
    int node = node0 + r;
    if (node < n) sIn[r][f] = h[(size_t)node * 32 + f];
    __syncthreads();

    float acc = b1[f];
    #pragma unroll
    for (int k = 0; k < 32; k++) acc += sIn[r][k] * sW1[k * 32 + f];
    acc = fmaxf(acc, 0.0f);
    sT[r][f] = acc;
    __syncthreads();

    if (f < 10) {
        float acc2 = b2[f];
        #pragma unroll
        for (int k = 0; k < 32; k++) acc2 += sT[r][k] * sW2[k * 10 + f];
        sZ[r][f] = acc2;
    }
    __syncthreads();

    if (f < 10 && node < n) {
        float mx = sZ[r][0];
        #pragma unroll
        for (int j = 1; j < 10; j++) mx = fmaxf(mx, sZ[r][j]);
        float s = 0.0f;
        #pragma unroll
        for (int j = 0; j < 10; j++) s += __expf(sZ[r][j] - mx);
        out[(size_t)node * 10 + f] = sZ[r][f] - mx - logf(s);
    }
}

// ---------------------------------------------------------------------------
extern "C" void kernel_launch(void* const* d_in, const int* in_sizes, int n_in,
                              void* d_out, int out_size, void* d_ws, size_t ws_size,
                              hipStream_t stream) {
    const float* x   = (const float*)d_in[0];
    const int*   ei  = (const int*)d_in[1];
    const float* W1a = (const float*)d_in[2];
    const float* b1a = (const float*)d_in[3];
    const float* W1b = (const float*)d_in[4];
    const float* b1b = (const float*)d_in[5];
    const float* W2a = (const float*)d_in[6];
    const float* b2a = (const float*)d_in[7];
    const float* W2b = (const float*)d_in[8];
    const float* b2b = (const float*)d_in[9];
    const float* W3a = (const float*)d_in[10];
    const float* b3a = (const float*)d_in[11];
    const float* W3b = (const float*)d_in[12];
    const float* b3b = (const float*)d_in[13];
    const float* g1  = (const float*)d_in[14];
    const float* be1 = (const float*)d_in[15];
    const float* m1  = (const float*)d_in[16];
    const float* v1  = (const float*)d_in[17];
    const float* g2  = (const float*)d_in[18];
    const float* be2 = (const float*)d_in[19];
    const float* m2  = (const float*)d_in[20];
    const float* v2  = (const float*)d_in[21];
    const float* g3  = (const float*)d_in[22];
    const float* be3 = (const float*)d_in[23];
    const float* m3  = (const float*)d_in[24];
    const float* v3  = (const float*)d_in[25];
    const float* Wf1 = (const float*)d_in[26];
    const float* bf1 = (const float*)d_in[27];
    const float* Wf2 = (const float*)d_in[28];
    const float* bf2 = (const float*)d_in[29];

    const int n = in_sizes[0] / 128;  // 50000
    const int E = in_sizes[1] / 2;    // 800000
    const int* src = ei;
    const int* dst = ei + E;

    float* agg128 = (float*)d_ws;
    float* h1     = agg128 + (size_t)n * 128;
    float* agg32  = h1 + (size_t)n * 32;
    float* h2     = agg32 + (size_t)n * 32;
    // h3 reuses h1's buffer
    float* out = (float*)d_out;

    const int nodeBlocks = (n + 7) / 8;

    // ---- Layer 1 ----
    hipMemsetAsync(agg128, 0, (size_t)n * 128 * sizeof(float), stream);
    {
        long long threads = (long long)E * 32;
        scatter128<<<(int)((threads + 255) / 256), 256, 0, stream>>>(x, src, dst, agg128, E);
    }
    mlp_layer1<<<nodeBlocks, 256, 0, stream>>>(x, agg128, W1a, b1a, W1b, b1b,
                                               g1, be1, m1, v1, h1, n);

    // ---- Layer 2 ----
    hipMemsetAsync(agg32, 0, (size_t)n * 32 * sizeof(float), stream);
    {
        long long threads = (long long)E * 8;
        scatter32<<<(int)((threads + 255) / 256), 256, 0, stream>>>(h1, src, dst, agg32, E);
    }
    mlp_layer32<<<nodeBlocks, 256, 0, stream>>>(h1, agg32, W2a, b2a, W2b, b2b,
                                                g2, be2, m2, v2, h2, n);

    // ---- Layer 3 ----
    hipMemsetAsync(agg32, 0, (size_t)n * 32 * sizeof(float), stream);
    {
        long long threads = (long long)E * 8;
        scatter32<<<(int)((threads + 255) / 256), 256, 0, stream>>>(h2, src, dst, agg32, E);
    }
    mlp_layer32<<<nodeBlocks, 256, 0, stream>>>(h2, agg32, W3a, b3a, W3b, b3b,
                                                g3, be3, m3, v3, h1, n);

    // ---- Final head ----
    final_head<<<nodeBlocks, 256, 0, stream>>>(h1, Wf1, bf1, Wf2, bf2, out, n);
}

// Round 4
// 372.693 us; speedup vs baseline: 5.5845x; 5.5845x over previous
//
#include <hip/hip_runtime.h>

#define BN_EPS 1e-5f

// ---------------------------------------------------------------------------
// z = x @ W (128 -> 32), no bias. block = 256 threads = 8 nodes x 32 lanes
// ---------------------------------------------------------------------------
__global__ void gemm128to32(const float* __restrict__ x, const float* __restrict__ W,
                            float* __restrict__ z, int n) {
    __shared__ float sW[128 * 32];
    __shared__ float sIn[8][128];
    int tid = threadIdx.x;
    for (int i = tid; i < 128 * 32; i += 256) sW[i] = W[i];
    int r = tid >> 5, f = tid & 31;
    int node = blockIdx.x * 8 + r;
    int c = f * 4;
    if (node < n) {
        const float4 xv = *reinterpret_cast<const float4*>(x + (size_t)node * 128 + c);
        sIn[r][c + 0] = xv.x;
        sIn[r][c + 1] = xv.y;
        sIn[r][c + 2] = xv.z;
        sIn[r][c + 3] = xv.w;
    }
    __syncthreads();
    float acc = 0.0f;
    #pragma unroll 8
    for (int k = 0; k < 128; k++) acc += sIn[r][k] * sW[k * 32 + f];
    if (node < n) z[(size_t)node * 32 + f] = acc;
}

// ---------------------------------------------------------------------------
// z = h @ W (32 -> 32), no bias
// ---------------------------------------------------------------------------
__global__ void gemm32(const float* __restrict__ h, const float* __restrict__ W,
                       float* __restrict__ z, int n) {
    __shared__ float sW[32 * 32];
    __shared__ float sIn[8][32];
    int tid = threadIdx.x;
    for (int i = tid; i < 1024; i += 256) sW[i] = W[i];
    int r = tid >> 5, f = tid & 31;
    int node = blockIdx.x * 8 + r;
    if (node < n) sIn[r][f] = h[(size_t)node * 32 + f];
    __syncthreads();
    float acc = 0.0f;
    #pragma unroll
    for (int k = 0; k < 32; k++) acc += sIn[r][k] * sW[k * 32 + f];
    if (node < n) z[(size_t)node * 32 + f] = acc;
}

// ---------------------------------------------------------------------------
// CSR build
// ---------------------------------------------------------------------------
__global__ void count_deg(const int* __restrict__ dst, int* __restrict__ deg, int E) {
    int e = blockIdx.x * blockDim.x + threadIdx.x;
    if (e < E) atomicAdd(&deg[dst[e]], 1);
}

// single block, 1024 threads: exclusive scan of deg -> rowstart, cursor
__global__ void scan_deg(const int* __restrict__ deg, int* __restrict__ rowstart,
                         int* __restrict__ cursor, int n, int E) {
    __shared__ int part[1024];
    int t = threadIdx.x;
    int chunk = (n + 1023) / 1024;
    int lo = t * chunk;
    int hi = lo + chunk;
    if (hi > n) hi = n;
    int s = 0;
    for (int i = lo; i < hi; i++) s += deg[i];
    part[t] = s;
    __syncthreads();
    // Hillis-Steele inclusive scan
    for (int off = 1; off < 1024; off <<= 1) {
        int v = (t >= off) ? part[t - off] : 0;
        __syncthreads();
        part[t] += v;
        __syncthreads();
    }
    int run = (t == 0) ? 0 : part[t - 1];
    for (int i = lo; i < hi; i++) {
        rowstart[i] = run;
        cursor[i] = run;
        run += deg[i];
    }
    if (t == 0) rowstart[n] = E;
}

__global__ void place_edges(const int* __restrict__ src, const int* __restrict__ dst,
                            int* __restrict__ cursor, int* __restrict__ ssrc, int E) {
    int e = blockIdx.x * blockDim.x + threadIdx.x;
    if (e >= E) return;
    int pos = atomicAdd(&cursor[dst[e]], 1);
    ssrc[pos] = src[e];
}

// ---------------------------------------------------------------------------
// Fused GIN layer (after pre-multiplying by Wa):
//   acc_i = z_i + sum_{j in N(i)} z_j            (gather via CSR)
//   t     = relu(acc + ba)
//   h     = relu(t @ Wb + bb)
//   out   = BN(h)
// block = 256 threads = 8 nodes x 32 lanes
// ---------------------------------------------------------------------------
__global__ void gin_fused(const float* __restrict__ z, const int* __restrict__ rowstart,
                          const int* __restrict__ ssrc,
                          const float* __restrict__ ba, const float* __restrict__ Wb,
                          const float* __restrict__ bb,
                          const float* __restrict__ g, const float* __restrict__ be,
                          const float* __restrict__ m, const float* __restrict__ v,
                          float* __restrict__ out, int n) {
    __shared__ float sWb[32 * 32];
    __shared__ float sT[8][32];
    int tid = threadIdx.x;
    for (int i = tid; i < 1024; i += 256) sWb[i] = Wb[i];
    int r = tid >> 5, f = tid & 31;
    int node = blockIdx.x * 8 + r;
    float acc = 0.0f;
    int j0 = 0, j1 = 0;
    if (node < n) {
        acc = z[(size_t)node * 32 + f];
        j0 = rowstart[node];
        j1 = rowstart[node + 1];
    }
    int j = j0;
    for (; j + 1 < j1; j += 2) {
        int s0 = ssrc[j];
        int s1 = ssrc[j + 1];
        float a0 = z[(size_t)s0 * 32 + f];
        float a1 = z[(size_t)s1 * 32 + f];
        acc += a0;
        acc += a1;
    }
    if (j < j1) acc += z[(size_t)ssrc[j] * 32 + f];

    float t = fmaxf(acc + ba[f], 0.0f);
    sT[r][f] = t;
    __syncthreads();

    float h = bb[f];
    #pragma unroll
    for (int k = 0; k < 32; k++) h += sT[r][k] * sWb[k * 32 + f];
    h = fmaxf(h, 0.0f);
    float bn = (h - m[f]) * rsqrtf(v[f] + BN_EPS) * g[f] + be[f];
    if (node < n) out[(size_t)node * 32 + f] = bn;
}

// ---------------------------------------------------------------------------
// Final head: out = log_softmax( relu(h @ Wf1 + bf1) @ Wf2 + bf2 )
// ---------------------------------------------------------------------------
__global__ void final_head(const float* __restrict__ h,
                           const float* __restrict__ W1, const float* __restrict__ b1,
                           const float* __restrict__ W2, const float* __restrict__ b2,
                           float* __restrict__ out, int n) {
    __shared__ float sW1[32 * 32];
    __shared__ float sW2[32 * 10];
    __shared__ float sIn[8][32];
    __shared__ float sT[8][32];
    __shared__ float sZ[8][12];

    int tid = threadIdx.x;
    for (int i = tid; i < 32 * 32; i += 256) sW1[i] = W1[i];
    for (int i = tid; i < 32 * 10; i += 256) sW2[i] = W2[i];

    int r = tid >> 5, f = tid & 31;
    int node = blockIdx.x * 8 + r;
    if (node < n) sIn[r][f] = h[(size_t)node * 32 + f];
    __syncthreads();

    float acc = b1[f];
    #pragma unroll
    for (int k = 0; k < 32; k++) acc += sIn[r][k] * sW1[k * 32 + f];
    acc = fmaxf(acc, 0.0f);
    sT[r][f] = acc;
    __syncthreads();

    if (f < 10) {
        float acc2 = b2[f];
        #pragma unroll
        for (int k = 0; k < 32; k++) acc2 += sT[r][k] * sW2[k * 10 + f];
        sZ[r][f] = acc2;
    }
    __syncthreads();

    if (f < 10 && node < n) {
        float mx = sZ[r][0];
        #pragma unroll
        for (int j = 1; j < 10; j++) mx = fmaxf(mx, sZ[r][j]);
        float s = 0.0f;
        #pragma unroll
        for (int j = 0; j < 10; j++) s += __expf(sZ[r][j] - mx);
        out[(size_t)node * 10 + f] = sZ[r][f] - mx - logf(s);
    }
}

// ---------------------------------------------------------------------------
extern "C" void kernel_launch(void* const* d_in, const int* in_sizes, int n_in,
                              void* d_out, int out_size, void* d_ws, size_t ws_size,
                              hipStream_t stream) {
    const float* x   = (const float*)d_in[0];
    const int*   ei  = (const int*)d_in[1];
    const float* W1a = (const float*)d_in[2];
    const float* b1a = (const float*)d_in[3];
    const float* W1b = (const float*)d_in[4];
    const float* b1b = (const float*)d_in[5];
    const float* W2a = (const float*)d_in[6];
    const float* b2a = (const float*)d_in[7];
    const float* W2b = (const float*)d_in[8];
    const float* b2b = (const float*)d_in[9];
    const float* W3a = (const float*)d_in[10];
    const float* b3a = (const float*)d_in[11];
    const float* W3b = (const float*)d_in[12];
    const float* b3b = (const float*)d_in[13];
    const float* g1  = (const float*)d_in[14];
    const float* be1 = (const float*)d_in[15];
    const float* m1  = (const float*)d_in[16];
    const float* v1  = (const float*)d_in[17];
    const float* g2  = (const float*)d_in[18];
    const float* be2 = (const float*)d_in[19];
    const float* m2  = (const float*)d_in[20];
    const float* v2  = (const float*)d_in[21];
    const float* g3  = (const float*)d_in[22];
    const float* be3 = (const float*)d_in[23];
    const float* m3  = (const float*)d_in[24];
    const float* v3  = (const float*)d_in[25];
    const float* Wf1 = (const float*)d_in[26];
    const float* bf1 = (const float*)d_in[27];
    const float* Wf2 = (const float*)d_in[28];
    const float* bf2 = (const float*)d_in[29];

    const int n = in_sizes[0] / 128;  // 50000
    const int E = in_sizes[1] / 2;    // 800000
    const int* src = ei;
    const int* dst = ei + E;

    // workspace layout: 3 float node buffers, then int CSR arrays
    float* z  = (float*)d_ws;                       // n*32 f
    float* hA = z + (size_t)n * 32;                 // n*32 f
    float* hB = hA + (size_t)n * 32;                // n*32 f
    int* deg      = (int*)(hB + (size_t)n * 32);    // n (also cursor's source)
    int* rowstart = deg + n;                        // n+1
    int* cursor   = rowstart + (n + 1);             // n
    int* ssrc     = cursor + n;                     // E

    float* out = (float*)d_out;
    const int nodeBlocks = (n + 7) / 8;
    const int edgeBlocks = (E + 255) / 256;

    // ---- CSR build ----
    hipMemsetAsync(deg, 0, (size_t)n * sizeof(int), stream);
    count_deg<<<edgeBlocks, 256, 0, stream>>>(dst, deg, E);
    scan_deg<<<1, 1024, 0, stream>>>(deg, rowstart, cursor, n, E);
    place_edges<<<edgeBlocks, 256, 0, stream>>>(src, dst, cursor, ssrc, E);

    // ---- Layer 1 (z = x @ W1a, then fused aggregate+MLP+BN) ----
    gemm128to32<<<nodeBlocks, 256, 0, stream>>>(x, W1a, z, n);
    gin_fused<<<nodeBlocks, 256, 0, stream>>>(z, rowstart, ssrc, b1a, W1b, b1b,
                                              g1, be1, m1, v1, hA, n);

    // ---- Layer 2 ----
    gemm32<<<nodeBlocks, 256, 0, stream>>>(hA, W2a, z, n);
    gin_fused<<<nodeBlocks, 256, 0, stream>>>(z, rowstart, ssrc, b2a, W2b, b2b,
                                              g2, be2, m2, v2, hB, n);

    // ---- Layer 3 ----
    gemm32<<<nodeBlocks, 256, 0, stream>>>(hB, W3a, z, n);
    gin_fused<<<nodeBlocks, 256, 0, stream>>>(z, rowstart, ssrc, b3a, W3b, b3b,
                                              g3, be3, m3, v3, hA, n);

    // ---- Final head ----
    final_head<<<nodeBlocks, 256, 0, stream>>>(hA, Wf1, bf1, Wf2, bf2, out, n);
}

// Round 5
// 250.890 us; speedup vs baseline: 8.2957x; 1.4855x over previous
//
#include <hip/hip_runtime.h>

#define BN_EPS 1e-5f
#define SCAN_CHUNK 1024  // elements per scan block (256 threads x 4)

// ---------------------------------------------------------------------------
// z = x @ W (128 -> 32), no bias. block = 256 threads = 8 nodes x 32 lanes
// ---------------------------------------------------------------------------
__global__ void gemm128to32(const float* __restrict__ x, const float* __restrict__ W,
                            float* __restrict__ z, int n) {
    __shared__ float sW[128 * 32];
    __shared__ float sIn[8][128];
    int tid = threadIdx.x;
    for (int i = tid; i < 128 * 32; i += 256) sW[i] = W[i];
    int r = tid >> 5, f = tid & 31;
    int node = blockIdx.x * 8 + r;
    int c = f * 4;
    if (node < n) {
        const float4 xv = *reinterpret_cast<const float4*>(x + (size_t)node * 128 + c);
        sIn[r][c + 0] = xv.x;
        sIn[r][c + 1] = xv.y;
        sIn[r][c + 2] = xv.z;
        sIn[r][c + 3] = xv.w;
    }
    __syncthreads();
    float acc = 0.0f;
    #pragma unroll 8
    for (int k = 0; k < 128; k++) acc += sIn[r][k] * sW[k * 32 + f];
    if (node < n) z[(size_t)node * 32 + f] = acc;
}

// ---------------------------------------------------------------------------
// z = h @ W (32 -> 32), no bias
// ---------------------------------------------------------------------------
__global__ void gemm32(const float* __restrict__ h, const float* __restrict__ W,
                       float* __restrict__ z, int n) {
    __shared__ float sW[32 * 32];
    __shared__ float sIn[8][32];
    int tid = threadIdx.x;
    for (int i = tid; i < 1024; i += 256) sW[i] = W[i];
    int r = tid >> 5, f = tid & 31;
    int node = blockIdx.x * 8 + r;
    if (node < n) sIn[r][f] = h[(size_t)node * 32 + f];
    __syncthreads();
    float acc = 0.0f;
    #pragma unroll
    for (int k = 0; k < 32; k++) acc += sIn[r][k] * sW[k * 32 + f];
    if (node < n) z[(size_t)node * 32 + f] = acc;
}

// ---------------------------------------------------------------------------
// CSR build
// ---------------------------------------------------------------------------
__global__ void count_deg(const int* __restrict__ dst, int* __restrict__ deg, int E) {
    int e = blockIdx.x * blockDim.x + threadIdx.x;
    if (e < E) atomicAdd(&deg[dst[e]], 1);
}

// per-chunk sums: block b sums deg[b*1024 .. b*1024+1023]
__global__ void chunk_sums(const int* __restrict__ deg, int* __restrict__ bsum, int n) {
    __shared__ int s[256];
    int b = blockIdx.x;
    int t = threadIdx.x;
    int i0 = b * SCAN_CHUNK + t * 4;
    int sum = 0;
    #pragma unroll
    for (int k = 0; k < 4; k++) {
        int i = i0 + k;
        if (i < n) sum += deg[i];
    }
    s[t] = sum;
    __syncthreads();
    for (int off = 128; off > 0; off >>= 1) {
        if (t < off) s[t] += s[t + off];
        __syncthreads();
    }
    if (t == 0) bsum[b] = s[0];
}

// single block: exclusive scan of chunk sums (nb <= 1024)
__global__ void scan_bsums(const int* __restrict__ bsum, int* __restrict__ boff,
                           int nb, int* __restrict__ rowstart, int n, int E) {
    __shared__ int s[1024];
    int t = threadIdx.x;
    s[t] = (t < nb) ? bsum[t] : 0;
    __syncthreads();
    for (int off = 1; off < 1024; off <<= 1) {
        int v = (t >= off) ? s[t - off] : 0;
        __syncthreads();
        s[t] += v;
        __syncthreads();
    }
    if (t < nb) boff[t] = (t == 0) ? 0 : s[t - 1];
    if (t == 0) rowstart[n] = E;
}

// block b: exclusive scan within its chunk + boff[b]; writes rowstart & cursor
__global__ void apply_scan(const int* __restrict__ deg, const int* __restrict__ boff,
                           int* __restrict__ rowstart, int* __restrict__ cursor, int n) {
    __shared__ int s[256];
    int b = blockIdx.x;
    int t = threadIdx.x;
    int i0 = b * SCAN_CHUNK + t * 4;
    int d0 = (i0 + 0 < n) ? deg[i0 + 0] : 0;
    int d1 = (i0 + 1 < n) ? deg[i0 + 1] : 0;
    int d2 = (i0 + 2 < n) ? deg[i0 + 2] : 0;
    int d3 = (i0 + 3 < n) ? deg[i0 + 3] : 0;
    s[t] = d0 + d1 + d2 + d3;
    __syncthreads();
    for (int off = 1; off < 256; off <<= 1) {
        int v = (t >= off) ? s[t - off] : 0;
        __syncthreads();
        s[t] += v;
        __syncthreads();
    }
    int pre = boff[b] + ((t == 0) ? 0 : s[t - 1]);
    int r0 = pre;
    int r1 = r0 + d0;
    int r2 = r1 + d1;
    int r3 = r2 + d2;
    if (i0 + 0 < n) { rowstart[i0 + 0] = r0; cursor[i0 + 0] = r0; }
    if (i0 + 1 < n) { rowstart[i0 + 1] = r1; cursor[i0 + 1] = r1; }
    if (i0 + 2 < n) { rowstart[i0 + 2] = r2; cursor[i0 + 2] = r2; }
    if (i0 + 3 < n) { rowstart[i0 + 3] = r3; cursor[i0 + 3] = r3; }
}

__global__ void place_edges(const int* __restrict__ src, const int* __restrict__ dst,
                            int* __restrict__ cursor, int* __restrict__ ssrc, int E) {
    int e = blockIdx.x * blockDim.x + threadIdx.x;
    if (e >= E) return;
    int pos = atomicAdd(&cursor[dst[e]], 1);
    ssrc[pos] = src[e];
}

// ---------------------------------------------------------------------------
// Fused GIN layer (after pre-multiplying by Wa):
//   acc_i = z_i + sum_{j in N(i)} z_j            (gather via CSR)
//   t     = relu(acc + ba);  h = relu(t @ Wb + bb);  out = BN(h)
// block = 256 threads = 8 nodes x 32 lanes
// ---------------------------------------------------------------------------
__global__ void gin_fused(const float* __restrict__ z, const int* __restrict__ rowstart,
                          const int* __restrict__ ssrc,
                          const float* __restrict__ ba, const float* __restrict__ Wb,
                          const float* __restrict__ bb,
                          const float* __restrict__ g, const float* __restrict__ be,
                          const float* __restrict__ m, const float* __restrict__ v,
                          float* __restrict__ out, int n) {
    __shared__ float sWb[32 * 32];
    __shared__ float sT[8][32];
    int tid = threadIdx.x;
    for (int i = tid; i < 1024; i += 256) sWb[i] = Wb[i];
    int r = tid >> 5, f = tid & 31;
    int node = blockIdx.x * 8 + r;
    float acc = 0.0f;
    int j0 = 0, j1 = 0;
    if (node < n) {
        acc = z[(size_t)node * 32 + f];
        j0 = rowstart[node];
        j1 = rowstart[node + 1];
    }
    float a0 = 0.0f, a1 = 0.0f, a2 = 0.0f, a3 = 0.0f;
    int j = j0;
    for (; j + 3 < j1; j += 4) {
        int s0 = ssrc[j];
        int s1 = ssrc[j + 1];
        int s2 = ssrc[j + 2];
        int s3 = ssrc[j + 3];
        a0 += z[(size_t)s0 * 32 + f];
        a1 += z[(size_t)s1 * 32 + f];
        a2 += z[(size_t)s2 * 32 + f];
        a3 += z[(size_t)s3 * 32 + f];
    }
    for (; j < j1; j++) acc += z[(size_t)ssrc[j] * 32 + f];
    acc += (a0 + a1) + (a2 + a3);

    float t = fmaxf(acc + ba[f], 0.0f);
    sT[r][f] = t;
    __syncthreads();

    float h = bb[f];
    #pragma unroll
    for (int k = 0; k < 32; k++) h += sT[r][k] * sWb[k * 32 + f];
    h = fmaxf(h, 0.0f);
    float bn = (h - m[f]) * rsqrtf(v[f] + BN_EPS) * g[f] + be[f];
    if (node < n) out[(size_t)node * 32 + f] = bn;
}

// ---------------------------------------------------------------------------
// Final head: out = log_softmax( relu(h @ Wf1 + bf1) @ Wf2 + bf2 )
// ---------------------------------------------------------------------------
__global__ void final_head(const float* __restrict__ h,
                           const float* __restrict__ W1, const float* __restrict__ b1,
                           const float* __restrict__ W2, const float* __restrict__ b2,
                           float* __restrict__ out, int n) {
    __shared__ float sW1[32 * 32];
    __shared__ float sW2[32 * 10];
    __shared__ float sIn[8][32];
    __shared__ float sT[8][32];
    __shared__ float sZ[8][12];

    int tid = threadIdx.x;
    for (int i = tid; i < 32 * 32; i += 256) sW1[i] = W1[i];
    for (int i = tid; i < 32 * 10; i += 256) sW2[i] = W2[i];

    int r = tid >> 5, f = tid & 31;
    int node = blockIdx.x * 8 + r;
    if (node < n) sIn[r][f] = h[(size_t)node * 32 + f];
    __syncthreads();

    float acc = b1[f];
    #pragma unroll
    for (int k = 0; k < 32; k++) acc += sIn[r][k] * sW1[k * 32 + f];
    acc = fmaxf(acc, 0.0f);
    sT[r][f] = acc;
    __syncthreads();

    if (f < 10) {
        float acc2 = b2[f];
        #pragma unroll
        for (int k = 0; k < 32; k++) acc2 += sT[r][k] * sW2[k * 10 + f];
        sZ[r][f] = acc2;
    }
    __syncthreads();

    if (f < 10 && node < n) {
        float mx = sZ[r][0];
        #pragma unroll
        for (int j = 1; j < 10; j++) mx = fmaxf(mx, sZ[r][j]);
        float s = 0.0f;
        #pragma unroll
        for (int j = 0; j < 10; j++) s += __expf(sZ[r][j] - mx);
        out[(size_t)node * 10 + f] = sZ[r][f] - mx - logf(s);
    }
}

// ---------------------------------------------------------------------------
extern "C" void kernel_launch(void* const* d_in, const int* in_sizes, int n_in,
                              void* d_out, int out_size, void* d_ws, size_t ws_size,
                              hipStream_t stream) {
    const float* x   = (const float*)d_in[0];
    const int*   ei  = (const int*)d_in[1];
    const float* W1a = (const float*)d_in[2];
    const float* b1a = (const float*)d_in[3];
    const float* W1b = (const float*)d_in[4];
    const float* b1b = (const float*)d_in[5];
    const float* W2a = (const float*)d_in[6];
    const float* b2a = (const float*)d_in[7];
    const float* W2b = (const float*)d_in[8];
    const float* b2b = (const float*)d_in[9];
    const float* W3a = (const float*)d_in[10];
    const float* b3a = (const float*)d_in[11];
    const float* W3b = (const float*)d_in[12];
    const float* b3b = (const float*)d_in[13];
    const float* g1  = (const float*)d_in[14];
    const float* be1 = (const float*)d_in[15];
    const float* m1  = (const float*)d_in[16];
    const float* v1  = (const float*)d_in[17];
    const float* g2  = (const float*)d_in[18];
    const float* be2 = (const float*)d_in[19];
    const float* m2  = (const float*)d_in[20];
    const float* v2  = (const float*)d_in[21];
    const float* g3  = (const float*)d_in[22];
    const float* be3 = (const float*)d_in[23];
    const float* m3  = (const float*)d_in[24];
    const float* v3  = (const float*)d_in[25];
    const float* Wf1 = (const float*)d_in[26];
    const float* bf1 = (const float*)d_in[27];
    const float* Wf2 = (const float*)d_in[28];
    const float* bf2 = (const float*)d_in[29];

    const int n = in_sizes[0] / 128;  // 50000
    const int E = in_sizes[1] / 2;    // 800000
    const int* src = ei;
    const int* dst = ei + E;

    // workspace layout
    float* z  = (float*)d_ws;                       // n*32 f
    float* hA = z + (size_t)n * 32;                 // n*32 f
    float* hB = hA + (size_t)n * 32;                // n*32 f
    int* deg      = (int*)(hB + (size_t)n * 32);    // n
    int* rowstart = deg + n;                        // n+1
    int* cursor   = rowstart + (n + 1);             // n
    int* ssrc     = cursor + n;                     // E
    int* bsum     = ssrc + E;                       // nb
    int* boff     = bsum + 1024;                    // nb

    float* out = (float*)d_out;
    const int nodeBlocks = (n + 7) / 8;
    const int edgeBlocks = (E + 255) / 256;
    const int nb = (n + SCAN_CHUNK - 1) / SCAN_CHUNK;

    // ---- CSR build ----
    hipMemsetAsync(deg, 0, (size_t)n * sizeof(int), stream);
    count_deg<<<edgeBlocks, 256, 0, stream>>>(dst, deg, E);
    chunk_sums<<<nb, 256, 0, stream>>>(deg, bsum, n);
    scan_bsums<<<1, 1024, 0, stream>>>(bsum, boff, nb, rowstart, n, E);
    apply_scan<<<nb, 256, 0, stream>>>(deg, boff, rowstart, cursor, n);
    place_edges<<<edgeBlocks, 256, 0, stream>>>(src, dst, cursor, ssrc, E);

    // ---- Layer 1 (z = x @ W1a, then fused aggregate+MLP+BN) ----
    gemm128to32<<<nodeBlocks, 256, 0, stream>>>(x, W1a, z, n);
    gin_fused<<<nodeBlocks, 256, 0, stream>>>(z, rowstart, ssrc, b1a, W1b, b1b,
                                              g1, be1, m1, v1, hA, n);

    // ---- Layer 2 ----
    gemm32<<<nodeBlocks, 256, 0, stream>>>(hA, W2a, z, n);
    gin_fused<<<nodeBlocks, 256, 0, stream>>>(z, rowstart, ssrc, b2a, W2b, b2b,
                                              g2, be2, m2, v2, hB, n);

    // ---- Layer 3 ----
    gemm32<<<nodeBlocks, 256, 0, stream>>>(hB, W3a, z, n);
    gin_fused<<<nodeBlocks, 256, 0, stream>>>(z, rowstart, ssrc, b3a, W3b, b3b,
                                              g3, be3, m3, v3, hA, n);

    // ---- Final head ----
    final_head<<<nodeBlocks, 256, 0, stream>>>(hA, Wf1, bf1, Wf2, bf2, out, n);
}

// Round 8
// 209.892 us; speedup vs baseline: 9.9161x; 1.1953x over previous
//
#include <hip/hip_runtime.h>

#define BN_EPS 1e-5f
#define SCAN_CHUNK 1024  // elements per scan block (256 threads x 4)

// ---------------------------------------------------------------------------
// z = x @ W (128 -> 32), no bias. block = 256 threads = 8 nodes x 32 lanes
// ---------------------------------------------------------------------------
__global__ void gemm128to32(const float* __restrict__ x, const float* __restrict__ W,
                            float* __restrict__ z, int n) {
    __shared__ float sW[128 * 32];
    __shared__ float sIn[8][128];
    int tid = threadIdx.x;
    for (int i = tid; i < 128 * 32; i += 256) sW[i] = W[i];
    int r = tid >> 5, f = tid & 31;
    int node = blockIdx.x * 8 + r;
    int c = f * 4;
    if (node < n) {
        const float4 xv = *reinterpret_cast<const float4*>(x + (size_t)node * 128 + c);
        sIn[r][c + 0] = xv.x;
        sIn[r][c + 1] = xv.y;
        sIn[r][c + 2] = xv.z;
        sIn[r][c + 3] = xv.w;
    }
    __syncthreads();
    float acc = 0.0f;
    #pragma unroll 8
    for (int k = 0; k < 128; k++) acc += sIn[r][k] * sW[k * 32 + f];
    if (node < n) z[(size_t)node * 32 + f] = acc;
}

// ---------------------------------------------------------------------------
// z = h @ W (32 -> 32), no bias
// ---------------------------------------------------------------------------
__global__ void gemm32(const float* __restrict__ h, const float* __restrict__ W,
                       float* __restrict__ z, int n) {
    __shared__ float sW[32 * 32];
    __shared__ float sIn[8][32];
    int tid = threadIdx.x;
    for (int i = tid; i < 1024; i += 256) sW[i] = W[i];
    int r = tid >> 5, f = tid & 31;
    int node = blockIdx.x * 8 + r;
    if (node < n) sIn[r][f] = h[(size_t)node * 32 + f];
    __syncthreads();
    float acc = 0.0f;
    #pragma unroll
    for (int k = 0; k < 32; k++) acc += sIn[r][k] * sW[k * 32 + f];
    if (node < n) z[(size_t)node * 32 + f] = acc;
}

// ---------------------------------------------------------------------------
// CSR build
// ---------------------------------------------------------------------------
__global__ void count_deg(const int* __restrict__ dst, int* __restrict__ deg, int E) {
    int e = blockIdx.x * blockDim.x + threadIdx.x;
    if (e < E) atomicAdd(&deg[dst[e]], 1);
}

// per-chunk sums: block b sums deg[b*1024 .. b*1024+1023]
__global__ void chunk_sums(const int* __restrict__ deg, int* __restrict__ bsum, int n) {
    __shared__ int s[256];
    int b = blockIdx.x;
    int t = threadIdx.x;
    int i0 = b * SCAN_CHUNK + t * 4;
    int sum = 0;
    #pragma unroll
    for (int k = 0; k < 4; k++) {
        int i = i0 + k;
        if (i < n) sum += deg[i];
    }
    s[t] = sum;
    __syncthreads();
    for (int off = 128; off > 0; off >>= 1) {
        if (t < off) s[t] += s[t + off];
        __syncthreads();
    }
    if (t == 0) bsum[b] = s[0];
}

// single block: exclusive scan of chunk sums (nb <= 1024)
__global__ void scan_bsums(const int* __restrict__ bsum, int* __restrict__ boff,
                           int nb, int* __restrict__ rowstart, int n, int E) {
    __shared__ int s[1024];
    int t = threadIdx.x;
    s[t] = (t < nb) ? bsum[t] : 0;
    __syncthreads();
    for (int off = 1; off < 1024; off <<= 1) {
        int v = (t >= off) ? s[t - off] : 0;
        __syncthreads();
        s[t] += v;
        __syncthreads();
    }
    if (t < nb) boff[t] = (t == 0) ? 0 : s[t - 1];
    if (t == 0) rowstart[n] = E;
}

// block b: exclusive scan within its chunk + boff[b]; writes rowstart & cursor
__global__ void apply_scan(const int* __restrict__ deg, const int* __restrict__ boff,
                           int* __restrict__ rowstart, int* __restrict__ cursor, int n) {
    __shared__ int s[256];
    int b = blockIdx.x;
    int t = threadIdx.x;
    int i0 = b * SCAN_CHUNK + t * 4;
    int d0 = (i0 + 0 < n) ? deg[i0 + 0] : 0;
    int d1 = (i0 + 1 < n) ? deg[i0 + 1] : 0;
    int d2 = (i0 + 2 < n) ? deg[i0 + 2] : 0;
    int d3 = (i0 + 3 < n) ? deg[i0 + 3] : 0;
    s[t] = d0 + d1 + d2 + d3;
    __syncthreads();
    for (int off = 1; off < 256; off <<= 1) {
        int v = (t >= off) ? s[t - off] : 0;
        __syncthreads();
        s[t] += v;
        __syncthreads();
    }
    int pre = boff[b] + ((t == 0) ? 0 : s[t - 1]);
    int r0 = pre;
    int r1 = r0 + d0;
    int r2 = r1 + d1;
    int r3 = r2 + d2;
    if (i0 + 0 < n) { rowstart[i0 + 0] = r0; cursor[i0 + 0] = r0; }
    if (i0 + 1 < n) { rowstart[i0 + 1] = r1; cursor[i0 + 1] = r1; }
    if (i0 + 2 < n) { rowstart[i0 + 2] = r2; cursor[i0 + 2] = r2; }
    if (i0 + 3 < n) { rowstart[i0 + 3] = r3; cursor[i0 + 3] = r3; }
}

// ---------------------------------------------------------------------------
// place_edges, XCD-range partitioned: block b serves dst-range (b%8) over
// edge-stripe (b/8). All writes to a given ssrc cache line then come from one
// XCD (blockIdx%8 round-robins over XCDs), so lines assemble fully in its L2
// instead of 4B-partial-dirtying 64B lines (52 MB -> ~4 MB HBM writes).
// ---------------------------------------------------------------------------
#define PE_STRIPES 160
__global__ void place_edges(const int* __restrict__ src, const int* __restrict__ dst,
                            int* __restrict__ cursor, int* __restrict__ ssrc,
                            int E, int n) {
    int g = blockIdx.x & 7;          // dst-range group == XCD (perf heuristic)
    int sb = blockIdx.x >> 3;        // edge stripe
    int rstep = (n + 7) / 8;
    int lo = g * rstep;
    int hi = lo + rstep; if (hi > n) hi = n;
    int per = (E + PE_STRIPES - 1) / PE_STRIPES;
    int e0 = sb * per;
    int e1 = e0 + per; if (e1 > E) e1 = E;
    for (int e = e0 + threadIdx.x; e < e1; e += blockDim.x) {
        int d = dst[e];
        if (d >= lo && d < hi) {
            int pos = atomicAdd(&cursor[d], 1);
            ssrc[pos] = src[e];
        }
    }
}

// ---------------------------------------------------------------------------
// Fused GIN layer (after pre-multiplying by Wa):
//   acc_i = z_i + sum_{j in N(i)} z_j   (CSR gather, float4 lanes)
//   t = relu(acc + ba);  h = relu(t @ Wb + bb);  out = BN(h)
// block = 256 threads = 32 nodes x 8 lanes; each lane owns 4 features.
// One gather instruction serves 8 nodes (1 KB/wave) vs 2 in the 32-lane
// layout -> ~4x fewer VMEM instructions on the latency-bound gather.
// ---------------------------------------------------------------------------
__global__ void gin_fused(const float* __restrict__ z, const int* __restrict__ rowstart,
                          const int* __restrict__ ssrc,
                          const float* __restrict__ ba, const float* __restrict__ Wb,
                          const float* __restrict__ bb,
                          const float* __restrict__ g, const float* __restrict__ be,
                          const float* __restrict__ m, const float* __restrict__ v,
                          float* __restrict__ out, int n) {
    __shared__ float sWb[32 * 32];   // [k][f], f contiguous
    __shared__ float sT[32][36];     // padded: bank = (4*grp + k) % 32, conflict-free
    int tid = threadIdx.x;
    for (int i = tid; i < 1024; i += 256) sWb[i] = Wb[i];
    int grp = tid >> 3;      // node within block
    int lane = tid & 7;
    int c = lane * 4;
    int node = blockIdx.x * 32 + grp;

    float4 acc = make_float4(0.f, 0.f, 0.f, 0.f);
    float4 acc2 = make_float4(0.f, 0.f, 0.f, 0.f);
    int j0 = 0, j1 = 0;
    if (node < n) {
        acc = *reinterpret_cast<const float4*>(z + (size_t)node * 32 + c);
        j0 = rowstart[node];
        j1 = rowstart[node + 1];
    }
    int j = j0;
    for (; j + 3 < j1; j += 4) {
        int s0 = ssrc[j];
        int s1 = ssrc[j + 1];
        int s2 = ssrc[j + 2];
        int s3 = ssrc[j + 3];
        float4 v0 = *reinterpret_cast<const float4*>(z + (size_t)s0 * 32 + c);
        float4 v1 = *reinterpret_cast<const float4*>(z + (size_t)s1 * 32 + c);
        float4 v2 = *reinterpret_cast<const float4*>(z + (size_t)s2 * 32 + c);
        float4 v3 = *reinterpret_cast<const float4*>(z + (size_t)s3 * 32 + c);
        acc.x += v0.x + v1.x; acc.y += v0.y + v1.y;
        acc.z += v0.z + v1.z; acc.w += v0.w + v1.w;
        acc2.x += v2.x + v3.x; acc2.y += v2.y + v3.y;
        acc2.z += v2.z + v3.z; acc2.w += v2.w + v3.w;
    }
    for (; j < j1; j++) {
        int s0 = ssrc[j];
        float4 v0 = *reinterpret_cast<const float4*>(z + (size_t)s0 * 32 + c);
        acc.x += v0.x; acc.y += v0.y; acc.z += v0.z; acc.w += v0.w;
    }
    acc.x += acc2.x; acc.y += acc2.y; acc.z += acc2.z; acc.w += acc2.w;

    const float4 bav = *reinterpret_cast<const float4*>(ba + c);
    sT[grp][c + 0] = fmaxf(acc.x + bav.x, 0.0f);
    sT[grp][c + 1] = fmaxf(acc.y + bav.y, 0.0f);
    sT[grp][c + 2] = fmaxf(acc.z + bav.z, 0.0f);
    sT[grp][c + 3] = fmaxf(acc.w + bav.w, 0.0f);
    __syncthreads();

    float4 h = *reinterpret_cast<const float4*>(bb + c);
    #pragma unroll
    for (int k = 0; k < 32; k++) {
        float tk = sT[grp][k];
        const float4 w = *reinterpret_cast<const float4*>(&sWb[k * 32 + c]);
        h.x += tk * w.x; h.y += tk * w.y; h.z += tk * w.z; h.w += tk * w.w;
    }
    const float4 mv = *reinterpret_cast<const float4*>(m + c);
    const float4 vv = *reinterpret_cast<const float4*>(v + c);
    const float4 gv = *reinterpret_cast<const float4*>(g + c);
    const float4 bev = *reinterpret_cast<const float4*>(be + c);
    float4 o;
    o.x = (fmaxf(h.x, 0.f) - mv.x) * rsqrtf(vv.x + BN_EPS) * gv.x + bev.x;
    o.y = (fmaxf(h.y, 0.f) - mv.y) * rsqrtf(vv.y + BN_EPS) * gv.y + bev.y;
    o.z = (fmaxf(h.z, 0.f) - mv.z) * rsqrtf(vv.z + BN_EPS) * gv.z + bev.z;
    o.w = (fmaxf(h.w, 0.f) - mv.w) * rsqrtf(vv.w + BN_EPS) * gv.w + bev.w;
    if (node < n) *reinterpret_cast<float4*>(out + (size_t)node * 32 + c) = o;
}

// ---------------------------------------------------------------------------
// Final head: out = log_softmax( relu(h @ Wf1 + bf1) @ Wf2 + bf2 )
// ---------------------------------------------------------------------------
__global__ void final_head(const float* __restrict__ h,
                           const float* __restrict__ W1, const float* __restrict__ b1,
                           const float* __restrict__ W2, const float* __restrict__ b2,
                           float* __restrict__ out, int n) {
    __shared__ float sW1[32 * 32];
    __shared__ float sW2[32 * 10];
    __shared__ float sIn[8][32];
    __shared__ float sT[8][32];
    __shared__ float sZ[8][12];

    int tid = threadIdx.x;
    for (int i = tid; i < 32 * 32; i += 256) sW1[i] = W1[i];
    for (int i = tid; i < 32 * 10; i += 256) sW2[i] = W2[i];

    int r = tid >> 5, f = tid & 31;
    int node = blockIdx.x * 8 + r;
    if (node < n) sIn[r][f] = h[(size_t)node * 32 + f];
    __syncthreads();

    float acc = b1[f];
    #pragma unroll
    for (int k = 0; k < 32; k++) acc += sIn[r][k] * sW1[k * 32 + f];
    acc = fmaxf(acc, 0.0f);
    sT[r][f] = acc;
    __syncthreads();

    if (f < 10) {
        float acc2 = b2[f];
        #pragma unroll
        for (int k = 0; k < 32; k++) acc2 += sT[r][k] * sW2[k * 10 + f];
        sZ[r][f] = acc2;
    }
    __syncthreads();

    if (f < 10 && node < n) {
        float mx = sZ[r][0];
        #pragma unroll
        for (int j = 1; j < 10; j++) mx = fmaxf(mx, sZ[r][j]);
        float s = 0.0f;
        #pragma unroll
        for (int j = 0; j < 10; j++) s += __expf(sZ[r][j] - mx);
        out[(size_t)node * 10 + f] = sZ[r][f] - mx - logf(s);
    }
}

// ---------------------------------------------------------------------------
extern "C" void kernel_launch(void* const* d_in, const int* in_sizes, int n_in,
                              void* d_out, int out_size, void* d_ws, size_t ws_size,
                              hipStream_t stream) {
    const float* x   = (const float*)d_in[0];
    const int*   ei  = (const int*)d_in[1];
    const float* W1a = (const float*)d_in[2];
    const float* b1a = (const float*)d_in[3];
    const float* W1b = (const float*)d_in[4];
    const float* b1b = (const float*)d_in[5];
    const float* W2a = (const float*)d_in[6];
    const float* b2a = (const float*)d_in[7];
    const float* W2b = (const float*)d_in[8];
    const float* b2b = (const float*)d_in[9];
    const float* W3a = (const float*)d_in[10];
    const float* b3a = (const float*)d_in[11];
    const float* W3b = (const float*)d_in[12];
    const float* b3b = (const float*)d_in[13];
    const float* g1  = (const float*)d_in[14];
    const float* be1 = (const float*)d_in[15];
    const float* m1  = (const float*)d_in[16];
    const float* v1  = (const float*)d_in[17];
    const float* g2  = (const float*)d_in[18];
    const float* be2 = (const float*)d_in[19];
    const float* m2  = (const float*)d_in[20];
    const float* v2  = (const float*)d_in[21];
    const float* g3  = (const float*)d_in[22];
    const float* be3 = (const float*)d_in[23];
    const float* m3  = (const float*)d_in[24];
    const float* v3  = (const float*)d_in[25];
    const float* Wf1 = (const float*)d_in[26];
    const float* bf1 = (const float*)d_in[27];
    const float* Wf2 = (const float*)d_in[28];
    const float* bf2 = (const float*)d_in[29];

    const int n = in_sizes[0] / 128;  // 50000
    const int E = in_sizes[1] / 2;    // 800000
    const int* src = ei;
    const int* dst = ei + E;

    // workspace layout
    float* z  = (float*)d_ws;                       // n*32 f
    float* hA = z + (size_t)n * 32;                 // n*32 f
    float* hB = hA + (size_t)n * 32;                // n*32 f
    int* deg      = (int*)(hB + (size_t)n * 32);    // n
    int* rowstart = deg + n;                        // n+1
    int* cursor   = rowstart + (n + 1);             // n
    int* ssrc     = cursor + n;                     // E
    int* bsum     = ssrc + E;                       // nb
    int* boff     = bsum + 1024;                    // nb

    float* out = (float*)d_out;
    const int nodeBlocks8  = (n + 7) / 8;
    const int nodeBlocks32 = (n + 31) / 32;
    const int edgeBlocks = (E + 255) / 256;
    const int nb = (n + SCAN_CHUNK - 1) / SCAN_CHUNK;

    // ---- CSR build ----
    hipMemsetAsync(deg, 0, (size_t)n * sizeof(int), stream);
    count_deg<<<edgeBlocks, 256, 0, stream>>>(dst, deg, E);
    chunk_sums<<<nb, 256, 0, stream>>>(deg, bsum, n);
    scan_bsums<<<1, 1024, 0, stream>>>(bsum, boff, nb, rowstart, n, E);
    apply_scan<<<nb, 256, 0, stream>>>(deg, boff, rowstart, cursor, n);
    place_edges<<<PE_STRIPES * 8, 256, 0, stream>>>(src, dst, cursor, ssrc, E, n);

    // ---- Layer 1 (z = x @ W1a, then fused aggregate+MLP+BN) ----
    gemm128to32<<<nodeBlocks8, 256, 0, stream>>>(x, W1a, z, n);
    gin_fused<<<nodeBlocks32, 256, 0, stream>>>(z, rowstart, ssrc, b1a, W1b, b1b,
                                                g1, be1, m1, v1, hA, n);

    // ---- Layer 2 ----
    gemm32<<<nodeBlocks8, 256, 0, stream>>>(hA, W2a, z, n);
    gin_fused<<<nodeBlocks32, 256, 0, stream>>>(z, rowstart, ssrc, b2a, W2b, b2b,
                                                g2, be2, m2, v2, hB, n);

    // ---- Layer 3 ----
    gemm32<<<nodeBlocks8, 256, 0, stream>>>(hB, W3a, z, n);
    gin_fused<<<nodeBlocks32, 256, 0, stream>>>(z, rowstart, ssrc, b3a, W3b, b3b,
                                                g3, be3, m3, v3, hA, n);

    // ---- Final head ----
    final_head<<<nodeBlocks8, 256, 0, stream>>>(hA, Wf1, bf1, Wf2, bf2, out, n);
}

// Round 9
// 177.442 us; speedup vs baseline: 11.7295x; 1.1829x over previous
//
#include <hip/hip_runtime.h>

#define BN_EPS 1e-5f
#define SCAN_CHUNK 1024  // elements per scan block (256 threads x 4)
#define PART_STRIPES 160 // edge stripes for XCD-partitioned atomics

// ---------------------------------------------------------------------------
// zero n4 int4's (replaces rocclr fillBuffer, which is 43us for 200KB)
// ---------------------------------------------------------------------------
__global__ void zero_ints(int* __restrict__ p, int n4) {
    int i = blockIdx.x * blockDim.x + threadIdx.x;
    if (i < n4) reinterpret_cast<int4*>(p)[i] = make_int4(0, 0, 0, 0);
}

// ---------------------------------------------------------------------------
// z = x @ W (128 -> 32), no bias. block = 256 threads = 8 nodes x 32 lanes
// ---------------------------------------------------------------------------
__global__ void gemm128to32(const float* __restrict__ x, const float* __restrict__ W,
                            float* __restrict__ z, int n) {
    __shared__ float sW[128 * 32];
    __shared__ float sIn[8][128];
    int tid = threadIdx.x;
    for (int i = tid; i < 128 * 32; i += 256) sW[i] = W[i];
    int r = tid >> 5, f = tid & 31;
    int node = blockIdx.x * 8 + r;
    int c = f * 4;
    if (node < n) {
        const float4 xv = *reinterpret_cast<const float4*>(x + (size_t)node * 128 + c);
        sIn[r][c + 0] = xv.x;
        sIn[r][c + 1] = xv.y;
        sIn[r][c + 2] = xv.z;
        sIn[r][c + 3] = xv.w;
    }
    __syncthreads();
    float acc = 0.0f;
    #pragma unroll 8
    for (int k = 0; k < 128; k++) acc += sIn[r][k] * sW[k * 32 + f];
    if (node < n) z[(size_t)node * 32 + f] = acc;
}

// ---------------------------------------------------------------------------
// CSR build — count_deg XCD-range partitioned: block (b%8) owns dst range,
// so each deg cache line takes atomics from one XCD only (L2-local).
// ---------------------------------------------------------------------------
__global__ void count_deg(const int* __restrict__ dst, int* __restrict__ deg,
                          int E, int n) {
    int g = blockIdx.x & 7;
    int sb = blockIdx.x >> 3;
    int rstep = (n + 7) / 8;
    int lo = g * rstep;
    int hi = lo + rstep; if (hi > n) hi = n;
    int per = (E + PART_STRIPES - 1) / PART_STRIPES;
    int e0 = sb * per;
    int e1 = e0 + per; if (e1 > E) e1 = E;
    for (int e = e0 + threadIdx.x; e < e1; e += blockDim.x) {
        int d = dst[e];
        if (d >= lo && d < hi) atomicAdd(&deg[d], 1);
    }
}

// per-chunk sums: block b sums deg[b*1024 .. b*1024+1023]
__global__ void chunk_sums(const int* __restrict__ deg, int* __restrict__ bsum, int n) {
    __shared__ int s[256];
    int b = blockIdx.x;
    int t = threadIdx.x;
    int i0 = b * SCAN_CHUNK + t * 4;
    int sum = 0;
    #pragma unroll
    for (int k = 0; k < 4; k++) {
        int i = i0 + k;
        if (i < n) sum += deg[i];
    }
    s[t] = sum;
    __syncthreads();
    for (int off = 128; off > 0; off >>= 1) {
        if (t < off) s[t] += s[t + off];
        __syncthreads();
    }
    if (t == 0) bsum[b] = s[0];
}

// single block: exclusive scan of chunk sums (nb <= 1024)
__global__ void scan_bsums(const int* __restrict__ bsum, int* __restrict__ boff,
                           int nb, int* __restrict__ rowstart, int n, int E) {
    __shared__ int s[1024];
    int t = threadIdx.x;
    s[t] = (t < nb) ? bsum[t] : 0;
    __syncthreads();
    for (int off = 1; off < 1024; off <<= 1) {
        int v = (t >= off) ? s[t - off] : 0;
        __syncthreads();
        s[t] += v;
        __syncthreads();
    }
    if (t < nb) boff[t] = (t == 0) ? 0 : s[t - 1];
    if (t == 0) rowstart[n] = E;
}

// block b: exclusive scan within its chunk + boff[b]; writes rowstart & cursor
__global__ void apply_scan(const int* __restrict__ deg, const int* __restrict__ boff,
                           int* __restrict__ rowstart, int* __restrict__ cursor, int n) {
    __shared__ int s[256];
    int b = blockIdx.x;
    int t = threadIdx.x;
    int i0 = b * SCAN_CHUNK + t * 4;
    int d0 = (i0 + 0 < n) ? deg[i0 + 0] : 0;
    int d1 = (i0 + 1 < n) ? deg[i0 + 1] : 0;
    int d2 = (i0 + 2 < n) ? deg[i0 + 2] : 0;
    int d3 = (i0 + 3 < n) ? deg[i0 + 3] : 0;
    s[t] = d0 + d1 + d2 + d3;
    __syncthreads();
    for (int off = 1; off < 256; off <<= 1) {
        int v = (t >= off) ? s[t - off] : 0;
        __syncthreads();
        s[t] += v;
        __syncthreads();
    }
    int pre = boff[b] + ((t == 0) ? 0 : s[t - 1]);
    int r0 = pre;
    int r1 = r0 + d0;
    int r2 = r1 + d1;
    int r3 = r2 + d2;
    if (i0 + 0 < n) { rowstart[i0 + 0] = r0; cursor[i0 + 0] = r0; }
    if (i0 + 1 < n) { rowstart[i0 + 1] = r1; cursor[i0 + 1] = r1; }
    if (i0 + 2 < n) { rowstart[i0 + 2] = r2; cursor[i0 + 2] = r2; }
    if (i0 + 3 < n) { rowstart[i0 + 3] = r3; cursor[i0 + 3] = r3; }
}

// ---------------------------------------------------------------------------
// place_edges, XCD-range partitioned (kills partial-line write amplification)
// ---------------------------------------------------------------------------
__global__ void place_edges(const int* __restrict__ src, const int* __restrict__ dst,
                            int* __restrict__ cursor, int* __restrict__ ssrc,
                            int E, int n) {
    int g = blockIdx.x & 7;
    int sb = blockIdx.x >> 3;
    int rstep = (n + 7) / 8;
    int lo = g * rstep;
    int hi = lo + rstep; if (hi > n) hi = n;
    int per = (E + PART_STRIPES - 1) / PART_STRIPES;
    int e0 = sb * per;
    int e1 = e0 + per; if (e1 > E) e1 = E;
    for (int e = e0 + threadIdx.x; e < e1; e += blockDim.x) {
        int d = dst[e];
        if (d >= lo && d < hi) {
            int pos = atomicAdd(&cursor[d], 1);
            ssrc[pos] = src[e];
        }
    }
}

// ---------------------------------------------------------------------------
// Mid GIN layer, fully fused (z = h_prev @ Wa precomputed):
//   acc = z_i + sum_j z_j; t = relu(acc+ba); H = relu(t@Wb+bb); o = BN(H)
//   zout = o @ Wnext_a      <- feeds the NEXT layer, no h round-trip
// block = 256 = 32 nodes x 8 lanes; lane owns 4 features.
// ---------------------------------------------------------------------------
__global__ void gin_fused_mid(const float* __restrict__ z, const int* __restrict__ rowstart,
                              const int* __restrict__ ssrc,
                              const float* __restrict__ ba, const float* __restrict__ Wb,
                              const float* __restrict__ bb,
                              const float* __restrict__ g, const float* __restrict__ be,
                              const float* __restrict__ m, const float* __restrict__ v,
                              const float* __restrict__ Wn, float* __restrict__ zout, int n) {
    __shared__ float sWb[1024];
    __shared__ float sWn[1024];
    __shared__ float sT[32][36];   // padded: bank = (4*grp+k)%32, conflict-free
    int tid = threadIdx.x;
    for (int i = tid; i < 1024; i += 256) { sWb[i] = Wb[i]; sWn[i] = Wn[i]; }
    int grp = tid >> 3, lane = tid & 7, c = lane * 4;
    int node = blockIdx.x * 32 + grp;

    float4 acc = make_float4(0.f, 0.f, 0.f, 0.f);
    float4 acc2 = make_float4(0.f, 0.f, 0.f, 0.f);
    int j0 = 0, j1 = 0;
    if (node < n) {
        acc = *reinterpret_cast<const float4*>(z + (size_t)node * 32 + c);
        j0 = rowstart[node];
        j1 = rowstart[node + 1];
    }
    int j = j0;
    for (; j + 3 < j1; j += 4) {
        int s0 = ssrc[j];
        int s1 = ssrc[j + 1];
        int s2 = ssrc[j + 2];
        int s3 = ssrc[j + 3];
        float4 v0 = *reinterpret_cast<const float4*>(z + (size_t)s0 * 32 + c);
        float4 v1 = *reinterpret_cast<const float4*>(z + (size_t)s1 * 32 + c);
        float4 v2 = *reinterpret_cast<const float4*>(z + (size_t)s2 * 32 + c);
        float4 v3 = *reinterpret_cast<const float4*>(z + (size_t)s3 * 32 + c);
        acc.x += v0.x + v1.x; acc.y += v0.y + v1.y;
        acc.z += v0.z + v1.z; acc.w += v0.w + v1.w;
        acc2.x += v2.x + v3.x; acc2.y += v2.y + v3.y;
        acc2.z += v2.z + v3.z; acc2.w += v2.w + v3.w;
    }
    for (; j < j1; j++) {
        int s0 = ssrc[j];
        float4 v0 = *reinterpret_cast<const float4*>(z + (size_t)s0 * 32 + c);
        acc.x += v0.x; acc.y += v0.y; acc.z += v0.z; acc.w += v0.w;
    }
    acc.x += acc2.x; acc.y += acc2.y; acc.z += acc2.z; acc.w += acc2.w;

    const float4 bav = *reinterpret_cast<const float4*>(ba + c);
    sT[grp][c + 0] = fmaxf(acc.x + bav.x, 0.0f);
    sT[grp][c + 1] = fmaxf(acc.y + bav.y, 0.0f);
    sT[grp][c + 2] = fmaxf(acc.z + bav.z, 0.0f);
    sT[grp][c + 3] = fmaxf(acc.w + bav.w, 0.0f);
    __syncthreads();

    float4 h = *reinterpret_cast<const float4*>(bb + c);
    #pragma unroll
    for (int k = 0; k < 32; k++) {
        float tk = sT[grp][k];
        const float4 w = *reinterpret_cast<const float4*>(&sWb[k * 32 + c]);
        h.x += tk * w.x; h.y += tk * w.y; h.z += tk * w.z; h.w += tk * w.w;
    }
    const float4 mv = *reinterpret_cast<const float4*>(m + c);
    const float4 vv = *reinterpret_cast<const float4*>(v + c);
    const float4 gv = *reinterpret_cast<const float4*>(g + c);
    const float4 bev = *reinterpret_cast<const float4*>(be + c);
    float4 o;
    o.x = (fmaxf(h.x, 0.f) - mv.x) * rsqrtf(vv.x + BN_EPS) * gv.x + bev.x;
    o.y = (fmaxf(h.y, 0.f) - mv.y) * rsqrtf(vv.y + BN_EPS) * gv.y + bev.y;
    o.z = (fmaxf(h.z, 0.f) - mv.z) * rsqrtf(vv.z + BN_EPS) * gv.z + bev.z;
    o.w = (fmaxf(h.w, 0.f) - mv.w) * rsqrtf(vv.w + BN_EPS) * gv.w + bev.w;
    __syncthreads();  // all reads of sT done before overwrite
    sT[grp][c + 0] = o.x;
    sT[grp][c + 1] = o.y;
    sT[grp][c + 2] = o.z;
    sT[grp][c + 3] = o.w;
    __syncthreads();

    float4 zq = make_float4(0.f, 0.f, 0.f, 0.f);
    #pragma unroll
    for (int k = 0; k < 32; k++) {
        float ok = sT[grp][k];
        const float4 w = *reinterpret_cast<const float4*>(&sWn[k * 32 + c]);
        zq.x += ok * w.x; zq.y += ok * w.y; zq.z += ok * w.z; zq.w += ok * w.w;
    }
    if (node < n) *reinterpret_cast<float4*>(zout + (size_t)node * 32 + c) = zq;
}

// ---------------------------------------------------------------------------
// Last GIN layer + head, fully fused:
//   o = BN(relu(relu(agg+ba)@Wb+bb));  t2 = relu(o@Wf1+bf1);
//   logits = t2@Wf2+bf2;  out = log_softmax(logits)
// ---------------------------------------------------------------------------
__global__ void gin_fused_last(const float* __restrict__ z, const int* __restrict__ rowstart,
                               const int* __restrict__ ssrc,
                               const float* __restrict__ ba, const float* __restrict__ Wb,
                               const float* __restrict__ bb,
                               const float* __restrict__ g, const float* __restrict__ be,
                               const float* __restrict__ m, const float* __restrict__ v,
                               const float* __restrict__ Wf1, const float* __restrict__ bf1,
                               const float* __restrict__ Wf2, const float* __restrict__ bf2,
                               float* __restrict__ out, int n) {
    __shared__ float sWb[1024];
    __shared__ float sW1[1024];
    __shared__ float sW2[320];
    __shared__ float sT[32][36];
    __shared__ float sZ[32][12];
    int tid = threadIdx.x;
    for (int i = tid; i < 1024; i += 256) { sWb[i] = Wb[i]; sW1[i] = Wf1[i]; }
    for (int i = tid; i < 320; i += 256) sW2[i] = Wf2[i];
    int grp = tid >> 3, lane = tid & 7, c = lane * 4;
    int node = blockIdx.x * 32 + grp;

    float4 acc = make_float4(0.f, 0.f, 0.f, 0.f);
    float4 acc2 = make_float4(0.f, 0.f, 0.f, 0.f);
    int j0 = 0, j1 = 0;
    if (node < n) {
        acc = *reinterpret_cast<const float4*>(z + (size_t)node * 32 + c);
        j0 = rowstart[node];
        j1 = rowstart[node + 1];
    }
    int j = j0;
    for (; j + 3 < j1; j += 4) {
        int s0 = ssrc[j];
        int s1 = ssrc[j + 1];
        int s2 = ssrc[j + 2];
        int s3 = ssrc[j + 3];
        float4 v0 = *reinterpret_cast<const float4*>(z + (size_t)s0 * 32 + c);
        float4 v1 = *reinterpret_cast<const float4*>(z + (size_t)s1 * 32 + c);
        float4 v2 = *reinterpret_cast<const float4*>(z + (size_t)s2 * 32 + c);
        float4 v3 = *reinterpret_cast<const float4*>(z + (size_t)s3 * 32 + c);
        acc.x += v0.x + v1.x; acc.y += v0.y + v1.y;
        acc.z += v0.z + v1.z; acc.w += v0.w + v1.w;
        acc2.x += v2.x + v3.x; acc2.y += v2.y + v3.y;
        acc2.z += v2.z + v3.z; acc2.w += v2.w + v3.w;
    }
    for (; j < j1; j++) {
        int s0 = ssrc[j];
        float4 v0 = *reinterpret_cast<const float4*>(z + (size_t)s0 * 32 + c);
        acc.x += v0.x; acc.y += v0.y; acc.z += v0.z; acc.w += v0.w;
    }
    acc.x += acc2.x; acc.y += acc2.y; acc.z += acc2.z; acc.w += acc2.w;

    const float4 bav = *reinterpret_cast<const float4*>(ba + c);
    sT[grp][c + 0] = fmaxf(acc.x + bav.x, 0.0f);
    sT[grp][c + 1] = fmaxf(acc.y + bav.y, 0.0f);
    sT[grp][c + 2] = fmaxf(acc.z + bav.z, 0.0f);
    sT[grp][c + 3] = fmaxf(acc.w + bav.w, 0.0f);
    __syncthreads();

    float4 h = *reinterpret_cast<const float4*>(bb + c);
    #pragma unroll
    for (int k = 0; k < 32; k++) {
        float tk = sT[grp][k];
        const float4 w = *reinterpret_cast<const float4*>(&sWb[k * 32 + c]);
        h.x += tk * w.x; h.y += tk * w.y; h.z += tk * w.z; h.w += tk * w.w;
    }
    const float4 mv = *reinterpret_cast<const float4*>(m + c);
    const float4 vv = *reinterpret_cast<const float4*>(v + c);
    const float4 gv = *reinterpret_cast<const float4*>(g + c);
    const float4 bev = *reinterpret_cast<const float4*>(be + c);
    float4 o;
    o.x = (fmaxf(h.x, 0.f) - mv.x) * rsqrtf(vv.x + BN_EPS) * gv.x + bev.x;
    o.y = (fmaxf(h.y, 0.f) - mv.y) * rsqrtf(vv.y + BN_EPS) * gv.y + bev.y;
    o.z = (fmaxf(h.z, 0.f) - mv.z) * rsqrtf(vv.z + BN_EPS) * gv.z + bev.z;
    o.w = (fmaxf(h.w, 0.f) - mv.w) * rsqrtf(vv.w + BN_EPS) * gv.w + bev.w;
    __syncthreads();
    sT[grp][c + 0] = o.x;
    sT[grp][c + 1] = o.y;
    sT[grp][c + 2] = o.z;
    sT[grp][c + 3] = o.w;
    __syncthreads();

    // t2 = relu(o @ Wf1 + bf1)
    float4 t2 = *reinterpret_cast<const float4*>(bf1 + c);
    #pragma unroll
    for (int k = 0; k < 32; k++) {
        float ok = sT[grp][k];
        const float4 w = *reinterpret_cast<const float4*>(&sW1[k * 32 + c]);
        t2.x += ok * w.x; t2.y += ok * w.y; t2.z += ok * w.z; t2.w += ok * w.w;
    }
    t2.x = fmaxf(t2.x, 0.f); t2.y = fmaxf(t2.y, 0.f);
    t2.z = fmaxf(t2.z, 0.f); t2.w = fmaxf(t2.w, 0.f);
    __syncthreads();
    sT[grp][c + 0] = t2.x;
    sT[grp][c + 1] = t2.y;
    sT[grp][c + 2] = t2.z;
    sT[grp][c + 3] = t2.w;
    __syncthreads();

    // logits: lane handles j = lane (+8 for lanes 0,1)
    for (int jj = lane; jj < 10; jj += 8) {
        float l = bf2[jj];
        #pragma unroll
        for (int k = 0; k < 32; k++) l += sT[grp][k] * sW2[k * 10 + jj];
        sZ[grp][jj] = l;
    }
    __syncthreads();

    if (node < n) {
        float mx = sZ[grp][0];
        #pragma unroll
        for (int jj = 1; jj < 10; jj++) mx = fmaxf(mx, sZ[grp][jj]);
        float s = 0.0f;
        #pragma unroll
        for (int jj = 0; jj < 10; jj++) s += __expf(sZ[grp][jj] - mx);
        float lse = mx + logf(s);
        for (int jj = lane; jj < 10; jj += 8)
            out[(size_t)node * 10 + jj] = sZ[grp][jj] - lse;
    }
}

// ---------------------------------------------------------------------------
extern "C" void kernel_launch(void* const* d_in, const int* in_sizes, int n_in,
                              void* d_out, int out_size, void* d_ws, size_t ws_size,
                              hipStream_t stream) {
    const float* x   = (const float*)d_in[0];
    const int*   ei  = (const int*)d_in[1];
    const float* W1a = (const float*)d_in[2];
    const float* b1a = (const float*)d_in[3];
    const float* W1b = (const float*)d_in[4];
    const float* b1b = (const float*)d_in[5];
    const float* W2a = (const float*)d_in[6];
    const float* b2a = (const float*)d_in[7];
    const float* W2b = (const float*)d_in[8];
    const float* b2b = (const float*)d_in[9];
    const float* W3a = (const float*)d_in[10];
    const float* b3a = (const float*)d_in[11];
    const float* W3b = (const float*)d_in[12];
    const float* b3b = (const float*)d_in[13];
    const float* g1  = (const float*)d_in[14];
    const float* be1 = (const float*)d_in[15];
    const float* m1  = (const float*)d_in[16];
    const float* v1  = (const float*)d_in[17];
    const float* g2  = (const float*)d_in[18];
    const float* be2 = (const float*)d_in[19];
    const float* m2  = (const float*)d_in[20];
    const float* v2  = (const float*)d_in[21];
    const float* g3  = (const float*)d_in[22];
    const float* be3 = (const float*)d_in[23];
    const float* m3  = (const float*)d_in[24];
    const float* v3  = (const float*)d_in[25];
    const float* Wf1 = (const float*)d_in[26];
    const float* bf1 = (const float*)d_in[27];
    const float* Wf2 = (const float*)d_in[28];
    const float* bf2 = (const float*)d_in[29];

    const int n = in_sizes[0] / 128;  // 50000
    const int E = in_sizes[1] / 2;    // 800000
    const int* src = ei;
    const int* dst = ei + E;

    // workspace layout
    float* zA = (float*)d_ws;                       // n*32 f
    float* zB = zA + (size_t)n * 32;                // n*32 f
    int* deg      = (int*)(zB + (size_t)n * 32);    // n
    int* rowstart = deg + n;                        // n+1
    int* cursor   = rowstart + (n + 1);             // n
    int* ssrc     = cursor + n;                     // E
    int* bsum     = ssrc + E;                       // nb
    int* boff     = bsum + 1024;                    // nb

    float* out = (float*)d_out;
    const int nodeBlocks8  = (n + 7) / 8;
    const int nodeBlocks32 = (n + 31) / 32;
    const int nb = (n + SCAN_CHUNK - 1) / SCAN_CHUNK;
    const int n4 = (n + 3) / 4;

    // ---- CSR build ----
    zero_ints<<<(n4 + 255) / 256, 256, 0, stream>>>(deg, n4);
    count_deg<<<PART_STRIPES * 8, 256, 0, stream>>>(dst, deg, E, n);
    chunk_sums<<<nb, 256, 0, stream>>>(deg, bsum, n);
    scan_bsums<<<1, 1024, 0, stream>>>(bsum, boff, nb, rowstart, n, E);
    apply_scan<<<nb, 256, 0, stream>>>(deg, boff, rowstart, cursor, n);
    place_edges<<<PART_STRIPES * 8, 256, 0, stream>>>(src, dst, cursor, ssrc, E, n);

    // ---- Layer 1: z1 = x @ W1a, then fused layer -> z2 ----
    gemm128to32<<<nodeBlocks8, 256, 0, stream>>>(x, W1a, zA, n);
    gin_fused_mid<<<nodeBlocks32, 256, 0, stream>>>(zA, rowstart, ssrc, b1a, W1b, b1b,
                                                    g1, be1, m1, v1, W2a, zB, n);
    // ---- Layer 2 -> z3 ----
    gin_fused_mid<<<nodeBlocks32, 256, 0, stream>>>(zB, rowstart, ssrc, b2a, W2b, b2b,
                                                    g2, be2, m2, v2, W3a, zA, n);
    // ---- Layer 3 + head -> out ----
    gin_fused_last<<<nodeBlocks32, 256, 0, stream>>>(zA, rowstart, ssrc, b3a, W3b, b3b,
                                                     g3, be3, m3, v3, Wf1, bf1, Wf2, bf2,
                                                     out, n);
}

// Round 11
// 166.431 us; speedup vs baseline: 12.5055x; 1.0662x over previous
//
#include <hip/hip_runtime.h>

#define BN_EPS 1e-5f
#define SCAN_CHUNK 1024  // elements per scan block (256 threads x 4)
#define PART_STRIPES 160 // edge stripes for XCD-partitioned atomics

// ---------------------------------------------------------------------------
// zero n4 int4's (replaces rocclr fillBuffer: 43us for 200KB at tiny grid)
// ---------------------------------------------------------------------------
__global__ void zero_ints(int* __restrict__ p, int n4) {
    int i = blockIdx.x * blockDim.x + threadIdx.x;
    if (i < n4) reinterpret_cast<int4*>(p)[i] = make_int4(0, 0, 0, 0);
}

// ---------------------------------------------------------------------------
// z = x @ W (128 -> 32), no bias.
// block = 256 threads = 32 nodes x 8 lanes; lane owns 4 output features.
// float4 LDS reads throughout (sIn padded to 132: bank base 132g%32 = 4g).
// ---------------------------------------------------------------------------
__global__ void gemm128to32(const float* __restrict__ x, const float* __restrict__ W,
                            float* __restrict__ z, int n) {
    __shared__ __align__(16) float sW[128 * 32];
    __shared__ __align__(16) float sIn[32][132];
    int tid = threadIdx.x;
    for (int i = tid; i < 128 * 32; i += 256)
        sW[i] = W[i];
    // stage 32 nodes x 128 feats (4096 floats) as float4
    {
        int base = blockIdx.x * 32;
        #pragma unroll
        for (int q = 0; q < 4; q++) {
            int flat = tid * 4 + q * 1024;
            int r = flat >> 7, cc = flat & 127;
            int node = base + r;
            float4 xv = make_float4(0.f, 0.f, 0.f, 0.f);
            if (node < n) xv = *reinterpret_cast<const float4*>(x + (size_t)node * 128 + cc);
            *reinterpret_cast<float4*>(&sIn[r][cc]) = xv;
        }
    }
    __syncthreads();

    int grp = tid >> 3, lane = tid & 7, c = lane * 4;
    int node = blockIdx.x * 32 + grp;
    float4 acc = make_float4(0.f, 0.f, 0.f, 0.f);
    #pragma unroll 8
    for (int k4 = 0; k4 < 32; k4++) {
        const float4 t4 = *reinterpret_cast<const float4*>(&sIn[grp][k4 * 4]);
        #pragma unroll
        for (int kk = 0; kk < 4; kk++) {
            float tk = (kk == 0) ? t4.x : (kk == 1) ? t4.y : (kk == 2) ? t4.z : t4.w;
            const float4 w = *reinterpret_cast<const float4*>(&sW[(k4 * 4 + kk) * 32 + c]);
            acc.x += tk * w.x; acc.y += tk * w.y; acc.z += tk * w.z; acc.w += tk * w.w;
        }
    }
    if (node < n) *reinterpret_cast<float4*>(z + (size_t)node * 32 + c) = acc;
}

// ---------------------------------------------------------------------------
// CSR build — count_deg XCD-range partitioned (L2-local int atomics)
// ---------------------------------------------------------------------------
__global__ void count_deg(const int* __restrict__ dst, int* __restrict__ deg,
                          int E, int n) {
    int g = blockIdx.x & 7;
    int sb = blockIdx.x >> 3;
    int rstep = (n + 7) / 8;
    int lo = g * rstep;
    int hi = lo + rstep; if (hi > n) hi = n;
    int per = (E + PART_STRIPES - 1) / PART_STRIPES;
    int e0 = sb * per;
    int e1 = e0 + per; if (e1 > E) e1 = E;
    for (int e = e0 + threadIdx.x; e < e1; e += blockDim.x) {
        int d = dst[e];
        if (d >= lo && d < hi) atomicAdd(&deg[d], 1);
    }
}

// per-chunk sums: block b sums deg[b*1024 .. b*1024+1023]
__global__ void chunk_sums(const int* __restrict__ deg, int* __restrict__ bsum, int n) {
    __shared__ int s[256];
    int b = blockIdx.x;
    int t = threadIdx.x;
    int i0 = b * SCAN_CHUNK + t * 4;
    int sum = 0;
    #pragma unroll
    for (int k = 0; k < 4; k++) {
        int i = i0 + k;
        if (i < n) sum += deg[i];
    }
    s[t] = sum;
    __syncthreads();
    for (int off = 128; off > 0; off >>= 1) {
        if (t < off) s[t] += s[t + off];
        __syncthreads();
    }
    if (t == 0) bsum[b] = s[0];
}

// single wave (64 threads): exclusive scan of chunk sums (nb <= 64), no barriers
__global__ void scan_bsums(const int* __restrict__ bsum, int* __restrict__ boff,
                           int nb, int* __restrict__ rowstart, int n, int E) {
    int t = threadIdx.x;
    int orig = (t < nb) ? bsum[t] : 0;
    int v = orig;
    #pragma unroll
    for (int off = 1; off < 64; off <<= 1) {
        int u = __shfl_up(v, off, 64);
        if (t >= off) v += u;
    }
    if (t < nb) boff[t] = v - orig;   // exclusive
    if (t == 0) rowstart[n] = E;
}

// block b: exclusive scan within its chunk + boff[b]; writes rowstart & cursor
__global__ void apply_scan(const int* __restrict__ deg, const int* __restrict__ boff,
                           int* __restrict__ rowstart, int* __restrict__ cursor, int n) {
    __shared__ int s[256];
    int b = blockIdx.x;
    int t = threadIdx.x;
    int i0 = b * SCAN_CHUNK + t * 4;
    int d0 = (i0 + 0 < n) ? deg[i0 + 0] : 0;
    int d1 = (i0 + 1 < n) ? deg[i0 + 1] : 0;
    int d2 = (i0 + 2 < n) ? deg[i0 + 2] : 0;
    int d3 = (i0 + 3 < n) ? deg[i0 + 3] : 0;
    s[t] = d0 + d1 + d2 + d3;
    __syncthreads();
    for (int off = 1; off < 256; off <<= 1) {
        int v = (t >= off) ? s[t - off] : 0;
        __syncthreads();
        s[t] += v;
        __syncthreads();
    }
    int pre = boff[b] + ((t == 0) ? 0 : s[t - 1]);
    int r0 = pre;
    int r1 = r0 + d0;
    int r2 = r1 + d1;
    int r3 = r2 + d2;
    if (i0 + 0 < n) { rowstart[i0 + 0] = r0; cursor[i0 + 0] = r0; }
    if (i0 + 1 < n) { rowstart[i0 + 1] = r1; cursor[i0 + 1] = r1; }
    if (i0 + 2 < n) { rowstart[i0 + 2] = r2; cursor[i0 + 2] = r2; }
    if (i0 + 3 < n) { rowstart[i0 + 3] = r3; cursor[i0 + 3] = r3; }
}

// ---------------------------------------------------------------------------
// place_edges, XCD-range partitioned (kills partial-line write amplification)
// ---------------------------------------------------------------------------
__global__ void place_edges(const int* __restrict__ src, const int* __restrict__ dst,
                            int* __restrict__ cursor, int* __restrict__ ssrc,
                            int E, int n) {
    int g = blockIdx.x & 7;
    int sb = blockIdx.x >> 3;
    int rstep = (n + 7) / 8;
    int lo = g * rstep;
    int hi = lo + rstep; if (hi > n) hi = n;
    int per = (E + PART_STRIPES - 1) / PART_STRIPES;
    int e0 = sb * per;
    int e1 = e0 + per; if (e1 > E) e1 = E;
    for (int e = e0 + threadIdx.x; e < e1; e += blockDim.x) {
        int d = dst[e];
        if (d >= lo && d < hi) {
            int pos = atomicAdd(&cursor[d], 1);
            ssrc[pos] = src[e];
        }
    }
}

// ---------------------------------------------------------------------------
// gather macro body: acc/acc2 float4 pairs, unroll 8 / 2 / 1
// ---------------------------------------------------------------------------
#define GATHER_BODY(zptr)                                                        \
    int j = j0;                                                                  \
    for (; j + 7 < j1; j += 8) {                                                 \
        int s0 = ssrc[j];     int s1 = ssrc[j + 1];                              \
        int s2 = ssrc[j + 2]; int s3 = ssrc[j + 3];                              \
        int s4 = ssrc[j + 4]; int s5 = ssrc[j + 5];                              \
        int s6 = ssrc[j + 6]; int s7 = ssrc[j + 7];                              \
        float4 v0 = *reinterpret_cast<const float4*>(zptr + (size_t)s0 * 32 + c);\
        float4 v1 = *reinterpret_cast<const float4*>(zptr + (size_t)s1 * 32 + c);\
        float4 v2 = *reinterpret_cast<const float4*>(zptr + (size_t)s2 * 32 + c);\
        float4 v3 = *reinterpret_cast<const float4*>(zptr + (size_t)s3 * 32 + c);\
        float4 v4 = *reinterpret_cast<const float4*>(zptr + (size_t)s4 * 32 + c);\
        float4 v5 = *reinterpret_cast<const float4*>(zptr + (size_t)s5 * 32 + c);\
        float4 v6 = *reinterpret_cast<const float4*>(zptr + (size_t)s6 * 32 + c);\
        float4 v7 = *reinterpret_cast<const float4*>(zptr + (size_t)s7 * 32 + c);\
        acc.x += (v0.x + v1.x) + (v2.x + v3.x);                                  \
        acc.y += (v0.y + v1.y) + (v2.y + v3.y);                                  \
        acc.z += (v0.z + v1.z) + (v2.z + v3.z);                                  \
        acc.w += (v0.w + v1.w) + (v2.w + v3.w);                                  \
        acc2.x += (v4.x + v5.x) + (v6.x + v7.x);                                 \
        acc2.y += (v4.y + v5.y) + (v6.y + v7.y);                                 \
        acc2.z += (v4.z + v5.z) + (v6.z + v7.z);                                 \
        acc2.w += (v4.w + v5.w) + (v6.w + v7.w);                                 \
    }                                                                            \
    for (; j + 1 < j1; j += 2) {                                                 \
        int s0 = ssrc[j];     int s1 = ssrc[j + 1];                              \
        float4 v0 = *reinterpret_cast<const float4*>(zptr + (size_t)s0 * 32 + c);\
        float4 v1 = *reinterpret_cast<const float4*>(zptr + (size_t)s1 * 32 + c);\
        acc.x += v0.x + v1.x; acc.y += v0.y + v1.y;                              \
        acc.z += v0.z + v1.z; acc.w += v0.w + v1.w;                              \
    }                                                                            \
    if (j < j1) {                                                                \
        int s0 = ssrc[j];                                                        \
        float4 v0 = *reinterpret_cast<const float4*>(zptr + (size_t)s0 * 32 + c);\
        acc.x += v0.x; acc.y += v0.y; acc.z += v0.z; acc.w += v0.w;              \
    }                                                                            \
    acc.x += acc2.x; acc.y += acc2.y; acc.z += acc2.z; acc.w += acc2.w;

// 32x32 matmul from sT (float4 reads, conflict-free) against sWx, add into hv
#define MATMUL32(sWx, hv)                                                        \
    _Pragma("unroll")                                                            \
    for (int k4 = 0; k4 < 8; k4++) {                                             \
        const float4 t4 = *reinterpret_cast<const float4*>(&sT[grp][k4 * 4]);    \
        const float4 wa = *reinterpret_cast<const float4*>(&sWx[(k4 * 4 + 0) * 32 + c]); \
        const float4 wb = *reinterpret_cast<const float4*>(&sWx[(k4 * 4 + 1) * 32 + c]); \
        const float4 wc = *reinterpret_cast<const float4*>(&sWx[(k4 * 4 + 2) * 32 + c]); \
        const float4 wd = *reinterpret_cast<const float4*>(&sWx[(k4 * 4 + 3) * 32 + c]); \
        hv.x += t4.x * wa.x + t4.y * wb.x + t4.z * wc.x + t4.w * wd.x;           \
        hv.y += t4.x * wa.y + t4.y * wb.y + t4.z * wc.y + t4.w * wd.y;           \
        hv.z += t4.x * wa.z + t4.y * wb.z + t4.z * wc.z + t4.w * wd.z;           \
        hv.w += t4.x * wa.w + t4.y * wb.w + t4.z * wc.w + t4.w * wd.w;           \
    }

// ---------------------------------------------------------------------------
// Mid GIN layer, fully fused: zout = BN(relu(relu(agg+ba)@Wb+bb)) @ Wnext_a
// block = 256 = 32 nodes x 8 lanes; lane owns 4 features.
// ---------------------------------------------------------------------------
__global__ void gin_fused_mid(const float* __restrict__ z, const int* __restrict__ rowstart,
                              const int* __restrict__ ssrc,
                              const float* __restrict__ ba, const float* __restrict__ Wb,
                              const float* __restrict__ bb,
                              const float* __restrict__ g, const float* __restrict__ be,
                              const float* __restrict__ m, const float* __restrict__ v,
                              const float* __restrict__ Wn, float* __restrict__ zout, int n) {
    __shared__ __align__(16) float sWb[1024];
    __shared__ __align__(16) float sWn[1024];
    __shared__ __align__(16) float sT[32][36];   // 144B row stride: 16B-aligned, bank base 4g
    int tid = threadIdx.x;
    for (int i = tid; i < 1024; i += 256) { sWb[i] = Wb[i]; sWn[i] = Wn[i]; }
    int grp = tid >> 3, lane = tid & 7, c = lane * 4;
    int node = blockIdx.x * 32 + grp;

    float4 acc = make_float4(0.f, 0.f, 0.f, 0.f);
    float4 acc2 = make_float4(0.f, 0.f, 0.f, 0.f);
    int j0 = 0, j1 = 0;
    if (node < n) {
        acc = *reinterpret_cast<const float4*>(z + (size_t)node * 32 + c);
        j0 = rowstart[node];
        j1 = rowstart[node + 1];
    }
    GATHER_BODY(z)

    const float4 bav = *reinterpret_cast<const float4*>(ba + c);
    sT[grp][c + 0] = fmaxf(acc.x + bav.x, 0.0f);
    sT[grp][c + 1] = fmaxf(acc.y + bav.y, 0.0f);
    sT[grp][c + 2] = fmaxf(acc.z + bav.z, 0.0f);
    sT[grp][c + 3] = fmaxf(acc.w + bav.w, 0.0f);
    __syncthreads();

    float4 h = *reinterpret_cast<const float4*>(bb + c);
    MATMUL32(sWb, h)
    const float4 mv = *reinterpret_cast<const float4*>(m + c);
    const float4 vv = *reinterpret_cast<const float4*>(v + c);
    const float4 gv = *reinterpret_cast<const float4*>(g + c);
    const float4 bev = *reinterpret_cast<const float4*>(be + c);
    float4 o;
    o.x = (fmaxf(h.x, 0.f) - mv.x) * rsqrtf(vv.x + BN_EPS) * gv.x + bev.x;
    o.y = (fmaxf(h.y, 0.f) - mv.y) * rsqrtf(vv.y + BN_EPS) * gv.y + bev.y;
    o.z = (fmaxf(h.z, 0.f) - mv.z) * rsqrtf(vv.z + BN_EPS) * gv.z + bev.z;
    o.w = (fmaxf(h.w, 0.f) - mv.w) * rsqrtf(vv.w + BN_EPS) * gv.w + bev.w;
    __syncthreads();
    sT[grp][c + 0] = o.x;
    sT[grp][c + 1] = o.y;
    sT[grp][c + 2] = o.z;
    sT[grp][c + 3] = o.w;
    __syncthreads();

    float4 zq = make_float4(0.f, 0.f, 0.f, 0.f);
    MATMUL32(sWn, zq)
    if (node < n) *reinterpret_cast<float4*>(zout + (size_t)node * 32 + c) = zq;
}

// ---------------------------------------------------------------------------
// Last GIN layer + head: out = log_softmax(relu(BN(...)@Wf1+bf1)@Wf2+bf2)
// ---------------------------------------------------------------------------
__global__ void gin_fused_last(const float* __restrict__ z, const int* __restrict__ rowstart,
                               const int* __restrict__ ssrc,
                               const float* __restrict__ ba, const float* __restrict__ Wb,
                               const float* __restrict__ bb,
                               const float* __restrict__ g, const float* __restrict__ be,
                               const float* __restrict__ m, const float* __restrict__ v,
                               const float* __restrict__ Wf1, const float* __restrict__ bf1,
                               const float* __restrict__ Wf2, const float* __restrict__ bf2,
                               float* __restrict__ out, int n) {
    __shared__ __align__(16) float sWb[1024];
    __shared__ __align__(16) float sW1[1024];
    __shared__ float sW2[320];
    __shared__ __align__(16) float sT[32][36];
    __shared__ float sZ[32][12];
    int tid = threadIdx.x;
    for (int i = tid; i < 1024; i += 256) { sWb[i] = Wb[i]; sW1[i] = Wf1[i]; }
    for (int i = tid; i < 320; i += 256) sW2[i] = Wf2[i];
    int grp = tid >> 3, lane = tid & 7, c = lane * 4;
    int node = blockIdx.x * 32 + grp;

    float4 acc = make_float4(0.f, 0.f, 0.f, 0.f);
    float4 acc2 = make_float4(0.f, 0.f, 0.f, 0.f);
    int j0 = 0, j1 = 0;
    if (node < n) {
        acc = *reinterpret_cast<const float4*>(z + (size_t)node * 32 + c);
        j0 = rowstart[node];
        j1 = rowstart[node + 1];
    }
    GATHER_BODY(z)

    const float4 bav = *reinterpret_cast<const float4*>(ba + c);
    sT[grp][c + 0] = fmaxf(acc.x + bav.x, 0.0f);
    sT[grp][c + 1] = fmaxf(acc.y + bav.y, 0.0f);
    sT[grp][c + 2] = fmaxf(acc.z + bav.z, 0.0f);
    sT[grp][c + 3] = fmaxf(acc.w + bav.w, 0.0f);
    __syncthreads();

    float4 h = *reinterpret_cast<const float4*>(bb + c);
    MATMUL32(sWb, h)
    const float4 mv = *reinterpret_cast<const float4*>(m + c);
    const float4 vv = *reinterpret_cast<const float4*>(v + c);
    const float4 gv = *reinterpret_cast<const float4*>(g + c);
    const float4 bev = *reinterpret_cast<const float4*>(be + c);
    float4 o;
    o.x = (fmaxf(h.x, 0.f) - mv.x) * rsqrtf(vv.x + BN_EPS) * gv.x + bev.x;
    o.y = (fmaxf(h.y, 0.f) - mv.y) * rsqrtf(vv.y + BN_EPS) * gv.y + bev.y;
    o.z = (fmaxf(h.z, 0.f) - mv.z) * rsqrtf(vv.z + BN_EPS) * gv.z + bev.z;
    o.w = (fmaxf(h.w, 0.f) - mv.w) * rsqrtf(vv.w + BN_EPS) * gv.w + bev.w;
    __syncthreads();
    sT[grp][c + 0] = o.x;
    sT[grp][c + 1] = o.y;
    sT[grp][c + 2] = o.z;
    sT[grp][c + 3] = o.w;
    __syncthreads();

    float4 t2 = *reinterpret_cast<const float4*>(bf1 + c);
    MATMUL32(sW1, t2)
    t2.x = fmaxf(t2.x, 0.f); t2.y = fmaxf(t2.y, 0.f);
    t2.z = fmaxf(t2.z, 0.f); t2.w = fmaxf(t2.w, 0.f);
    __syncthreads();
    sT[grp][c + 0] = t2.x;
    sT[grp][c + 1] = t2.y;
    sT[grp][c + 2] = t2.z;
    sT[grp][c + 3] = t2.w;
    __syncthreads();

    // logits: lane handles jj = lane (+8 for lanes 0,1)
    for (int jj = lane; jj < 10; jj += 8) {
        float l = bf2[jj];
        #pragma unroll
        for (int k4 = 0; k4 < 8; k4++) {
            const float4 t4 = *reinterpret_cast<const float4*>(&sT[grp][k4 * 4]);
            l += t4.x * sW2[(k4 * 4 + 0) * 10 + jj];
            l += t4.y * sW2[(k4 * 4 + 1) * 10 + jj];
            l += t4.z * sW2[(k4 * 4 + 2) * 10 + jj];
            l += t4.w * sW2[(k4 * 4 + 3) * 10 + jj];
        }
        sZ[grp][jj] = l;
    }
    __syncthreads();

    if (node < n) {
        float mx = sZ[grp][0];
        #pragma unroll
        for (int jj = 1; jj < 10; jj++) mx = fmaxf(mx, sZ[grp][jj]);
        float s = 0.0f;
        #pragma unroll
        for (int jj = 0; jj < 10; jj++) s += __expf(sZ[grp][jj] - mx);
        float lse = mx + logf(s);
        for (int jj = lane; jj < 10; jj += 8)
            out[(size_t)node * 10 + jj] = sZ[grp][jj] - lse;
    }
}

// ---------------------------------------------------------------------------
extern "C" void kernel_launch(void* const* d_in, const int* in_sizes, int n_in,
                              void* d_out, int out_size, void* d_ws, size_t ws_size,
                              hipStream_t stream) {
    const float* x   = (const float*)d_in[0];
    const int*   ei  = (const int*)d_in[1];
    const float* W1a = (const float*)d_in[2];
    const float* b1a = (const float*)d_in[3];
    const float* W1b = (const float*)d_in[4];
    const float* b1b = (const float*)d_in[5];
    const float* W2a = (const float*)d_in[6];
    const float* b2a = (const float*)d_in[7];
    const float* W2b = (const float*)d_in[8];
    const float* b2b = (const float*)d_in[9];
    const float* W3a = (const float*)d_in[10];
    const float* b3a = (const float*)d_in[11];
    const float* W3b = (const float*)d_in[12];
    const float* b3b = (const float*)d_in[13];
    const float* g1  = (const float*)d_in[14];
    const float* be1 = (const float*)d_in[15];
    const float* m1  = (const float*)d_in[16];
    const float* v1  = (const float*)d_in[17];
    const float* g2  = (const float*)d_in[18];
    const float* be2 = (const float*)d_in[19];
    const float* m2  = (const float*)d_in[20];
    const float* v2  = (const float*)d_in[21];
    const float* g3  = (const float*)d_in[22];
    const float* be3 = (const float*)d_in[23];
    const float* m3  = (const float*)d_in[24];
    const float* v3  = (const float*)d_in[25];
    const float* Wf1 = (const float*)d_in[26];
    const float* bf1 = (const float*)d_in[27];
    const float* Wf2 = (const float*)d_in[28];
    const float* bf2 = (const float*)d_in[29];

    const int n = in_sizes[0] / 128;  // 50000
    const int E = in_sizes[1] / 2;    // 800000
    const int* src = ei;
    const int* dst = ei + E;

    // workspace layout
    float* zA = (float*)d_ws;                       // n*32 f
    float* zB = zA + (size_t)n * 32;                // n*32 f
    int* deg      = (int*)(zB + (size_t)n * 32);    // n
    int* rowstart = deg + n;                        // n+1
    int* cursor   = rowstart + (n + 1);             // n
    int* ssrc     = cursor + n;                     // E
    int* bsum     = ssrc + E;                       // nb
    int* boff     = bsum + 1024;                    // nb

    float* out = (float*)d_out;
    const int nodeBlocks32 = (n + 31) / 32;
    const int nb = (n + SCAN_CHUNK - 1) / SCAN_CHUNK;
    const int n4 = (n + 3) / 4;

    // ---- CSR build ----
    zero_ints<<<(n4 + 255) / 256, 256, 0, stream>>>(deg, n4);
    count_deg<<<PART_STRIPES * 8, 256, 0, stream>>>(dst, deg, E, n);
    chunk_sums<<<nb, 256, 0, stream>>>(deg, bsum, n);
    scan_bsums<<<1, 64, 0, stream>>>(bsum, boff, nb, rowstart, n, E);
    apply_scan<<<nb, 256, 0, stream>>>(deg, boff, rowstart, cursor, n);
    place_edges<<<PART_STRIPES * 8, 256, 0, stream>>>(src, dst, cursor, ssrc, E, n);

    // ---- Layer 1: z1 = x @ W1a, then fused layer -> z2 ----
    gemm128to32<<<nodeBlocks32, 256, 0, stream>>>(x, W1a, zA, n);
    gin_fused_mid<<<nodeBlocks32, 256, 0, stream>>>(zA, rowstart, ssrc, b1a, W1b, b1b,
                                                    g1, be1, m1, v1, W2a, zB, n);
    // ---- Layer 2 -> z3 ----
    gin_fused_mid<<<nodeBlocks32, 256, 0, stream>>>(zB, rowstart, ssrc, b2a, W2b, b2b,
                                                    g2, be2, m2, v2, W3a, zA, n);
    // ---- Layer 3 + head -> out ----
    gin_fused_last<<<nodeBlocks32, 256, 0, stream>>>(zA, rowstart, ssrc, b3a, W3b, b3b,
                                                     g3, be3, m3, v3, Wf1, bf1, Wf2, bf2,
                                                     out, n);
}